// Round 8
// baseline (443.592 us; speedup 1.0000x reference)
//
#include <hip/hip_runtime.h>

// LorentzBlock: B=2, L=2048, D=768, H=12, DH=64, DFF=3072
// R18: pipeline depth 3 (triple-buffer, vmcnt(8)) for ffn2/QKV/Wo.
// R17 post-mortem: FETCH 167->34MB confirmed XCD swizzle, but ffn2 stuck at
// 86us: loads now served by L2/L3 whose latency (~500cy) exceeds one K-iter
// (~330cy) -> depth-2 still stalls ~150-250cy/iter on vmcnt(4). Depth-3
// gives tile t two full iters to land. LDS 48KB = 3 blocks/CU, matching
// ffn2's grid-bound 3/CU. FFN1 keeps depth-2 (wants 5 blocks/CU).
// Keeps R17 XCD swizzle + R13 flash-decode.

typedef unsigned short u16;
typedef __bf16 bfrag __attribute__((ext_vector_type(8)));
typedef float f32x4 __attribute__((ext_vector_type(4)));

#define MFMA(a, b, c) __builtin_amdgcn_mfma_f32_16x16x32_bf16(a, b, c, 0, 0, 0)
#define NEG_BIG (-30000.0f)
#define ASYNC16(g, l)                                                        \
  __builtin_amdgcn_global_load_lds(                                          \
      (const __attribute__((address_space(1))) unsigned int*)(g),            \
      (__attribute__((address_space(3))) unsigned int*)(l), 16, 0, 0)

__device__ __forceinline__ float bf2f(u16 u) {
  unsigned int v = ((unsigned int)u) << 16;
  float f; __builtin_memcpy(&f, &v, 4); return f;
}
__device__ __forceinline__ u16 f2bf(float f) {
  unsigned int v; __builtin_memcpy(&v, &f, 4);
  v += 0x7fffu + ((v >> 16) & 1u);   // RNE
  return (u16)(v >> 16);
}
__device__ __forceinline__ bfrag ldfrag(const u16* p) {
  bfrag v; __builtin_memcpy(&v, p, 16); return v;
}

// XCD-chunked bijective swizzle of the linear workgroup id. Requires
// nwg % 8 == 0 (all call sites comply); identity fallback otherwise.
__device__ __forceinline__ int xcd_work_id() {
  const int nx = gridDim.x, ny = gridDim.y;
  const int nwg = nx * ny * gridDim.z;
  const int orig = blockIdx.x + nx * (blockIdx.y + ny * blockIdx.z);
  if (nwg & 7) return orig;
  return (orig & 7) * (nwg >> 3) + (orig >> 3);
}

// ---------------------------------------------------------------------------
// Mask canonicalization -> float[768].
// ---------------------------------------------------------------------------
__global__ __launch_bounds__(256) void mask_conv_k(const void* __restrict__ mask,
                                                   float* __restrict__ mfl) {
  __shared__ int msh;
  if (threadIdx.x == 0) msh = 0;
  __syncthreads();
  const unsigned int* w = (const unsigned int*)mask;
  if (threadIdx.x < 192) {
    const unsigned int v = w[threadIdx.x];
    if ((v & 0xFFFFu) == 0x3F80u) atomicOr(&msh, 4);
    else if (v == 0x3F800000u) atomicOr(&msh, 2);
    else if (v >= 2u) atomicOr(&msh, 1);
  }
  __syncthreads();
  const int m = msh;
  const int mode = (m & 4) ? 3 : (m & 2) ? 2 : (m & 1) ? 1 : 0;
  for (int i = threadIdx.x; i < 768; i += 256) {
    int b;
    if (mode == 3) b = ((const u16*)mask)[i] != 0;
    else if (mode == 2) b = ((const float*)mask)[i] != 0.0f;
    else if (mode == 1) b = ((const unsigned char*)mask)[i] != 0;
    else b = ((const int*)mask)[i] != 0;
    mfl[i] = (float)b;
  }
}

// ---------------------------------------------------------------------------
// Convert fp32 weight segments -> bf16 arena. mmode: 0 none, 1 *m[k],
// 2 *(1-m[k]) with k = i % 768 (mask fold for w1_t / w1_s).
// ---------------------------------------------------------------------------
struct Segs {
  const void* src[14];
  int off[14];
  int n[14];
  int mmode[14];
};

__global__ __launch_bounds__(256) void convert_k(Segs segs, u16* __restrict__ dstb,
                                                 const float* __restrict__ mfl) {
  const int seg = blockIdx.y;
  const int n = segs.n[seg];
  const int mm = segs.mmode[seg];
  u16* dst = dstb + segs.off[seg];
  const float* src = (const float*)segs.src[seg];
  for (int i = (blockIdx.x * 256 + threadIdx.x) * 4; i < n; i += gridDim.x * 1024) {
    float4 v;
    __builtin_memcpy(&v, src + i, 16);
    if (mm) {
      const int k = i % 768;
      float m0 = mfl[k], m1 = mfl[k + 1], m2 = mfl[k + 2], m3 = mfl[k + 3];
      if (mm == 2) { m0 = 1.f - m0; m1 = 1.f - m1; m2 = 1.f - m2; m3 = 1.f - m3; }
      v.x *= m0; v.y *= m1; v.z *= m2; v.w *= m3;
    }
    dst[i] = f2bf(v.x); dst[i + 1] = f2bf(v.y);
    dst[i + 2] = f2bf(v.z); dst[i + 3] = f2bf(v.w);
  }
}

// ---------------------------------------------------------------------------
// Minkowski LayerNorm. fp32 input, bf16 output. Optionally copies the raw
// input row to Xcopy (fp32) -- seeds d_out with x for the Wo split-K atomics.
// ---------------------------------------------------------------------------
__global__ __launch_bounds__(256) void mink_norm_k(
    const float* __restrict__ X, const float* __restrict__ mf,
    const u16* __restrict__ w, const u16* __restrict__ bias,
    u16* __restrict__ Y, float* __restrict__ Xcopy) {
  __shared__ float red[8];
  const int row = blockIdx.x, tid = threadIdx.x;
  const int wid = tid >> 6, lane = tid & 63;
  const size_t roff = (size_t)row * 768;

  float xv[3], mv[3];
  int idx[3];
#pragma unroll
  for (int i = 0; i < 3; i++) {
    idx[i] = tid + i * 256;
    xv[i] = X[roff + idx[i]];
    mv[i] = mf[idx[i]];
  }
  if (Xcopy) {
#pragma unroll
    for (int i = 0; i < 3; i++) Xcopy[roff + idx[i]] = xv[i];
  }
  float s = xv[0] + xv[1] + xv[2];
#pragma unroll
  for (int o = 32; o >= 1; o >>= 1) s += __shfl_xor(s, o, 64);
  if (lane == 0) red[wid] = s;
  __syncthreads();
  const float mean = (red[0] + red[1] + red[2] + red[3]) * (1.0f / 768.0f);
  __syncthreads();

  float xc[3], ss = 0.0f, sm = 0.0f;
#pragma unroll
  for (int i = 0; i < 3; i++) {
    xc[i] = xv[i] - mean;
    ss += xc[i] * xc[i];
    sm += xc[i] * xc[i] * mv[i];
  }
#pragma unroll
  for (int o = 32; o >= 1; o >>= 1) {
    ss += __shfl_xor(ss, o, 64);
    sm += __shfl_xor(sm, o, 64);
  }
  if (lane == 0) { red[wid] = ss; red[4 + wid] = sm; }
  __syncthreads();
  const float sumsq = red[0] + red[1] + red[2] + red[3];
  const float summ = red[4] + red[5] + red[6] + red[7];
  const float var = sumsq * (1.0f / 768.0f);
  const float eta = sumsq - 2.0f * summ;
  const float rs = 1.0f / sqrtf(var + 1e-5f);
  const float re = 1.0f / sqrtf(fabsf(eta) + 1e-5f);

#pragma unroll
  for (int i = 0; i < 3; i++) {
    const float xn = xc[i] * 0.5f * (rs + re);
    Y[roff + idx[i]] = f2bf(bf2f(w[idx[i]]) * xn + bf2f(bias[idx[i]]));
  }
}

// ---------------------------------------------------------------------------
// Q Lorentz correction, in place. 4 rows per block (one per wave).
// ---------------------------------------------------------------------------
__global__ __launch_bounds__(256) void qcorr_k(u16* __restrict__ Q,
                                               const float* __restrict__ mf) {
  const int idx = blockIdx.x * 4 + (threadIdx.x >> 6);  // (b*2048+l)*12+h
  const int t = threadIdx.x & 63;
  const int h = idx % 12;
  const int bl = idx / 12;
  const size_t off = (size_t)bl * 768 + h * 64 + t;
  const float q = bf2f(Q[off]);
  const float m = mf[h * 64 + t];
  float q2 = q * q, qm2 = q * q * m;
#pragma unroll
  for (int o = 32; o >= 1; o >>= 1) {
    q2 += __shfl_xor(q2, o, 64);
    qm2 += __shfl_xor(qm2, o, 64);
  }
  const float qn = sqrtf(q2), qtn = sqrtf(qm2);
  const float sf = (qtn > 1e-6f) ? qn / fmaxf(qtn, 1e-8f) : 0.0f;
  Q[off] = f2bf(q * (1.0f - 0.5f * sf * m) * 0.125f);
}

// ---------------------------------------------------------------------------
// 128x128 MFMA GEMM core, DEPTH-buffered counted-vmcnt pipeline.
// As/Bs are [DEPTH*128][32]. Per K-iter t:
//   STAGE(tile t+DEPTH-1 -> buf (t+DEPTH-1)%DEPTH)
//   vmcnt(4*(DEPTH-1))   (tile t landed; newer tiles stay in flight)
//   s_barrier; ds_read buf[t%DEPTH] + 16 MFMA
//   lgkmcnt(0)+sched_barrier(0); s_barrier
// Tail ladder: DEPTH==3 -> vmcnt(4) then vmcnt(0). Never over-drains.
// ---------------------------------------------------------------------------
template <int DEPTH>
__device__ __forceinline__ void gemm128_loop(
    const u16* __restrict__ Ab, const u16* __restrict__ Wb2,
    int K, int lda, int ldb, u16 (*As)[32], u16 (*Bs)[32], f32x4 acc[4][4]) {
  const int tid = threadIdx.x;
  const int wid = tid >> 6, lane = tid & 63;
  const int lr = lane & 15, lq = lane >> 4;
  const int srow = wid * 32 + (lane >> 2);
  const int scol = (lane & 3) * 8;
  const u16* ga0 = Ab + (size_t)srow * lda + scol;
  const u16* ga1 = Ab + (size_t)(srow + 16) * lda + scol;
  const u16* gb0 = Wb2 + (size_t)srow * ldb + scol;
  const u16* gb1 = Wb2 + (size_t)(srow + 16) * ldb + scol;
  const int wr = (wid >> 1) * 64, wc = (wid & 1) * 64;
  const int nt = K >> 5;

#define STAGE16(dbuf, k0)                                                    \
  {                                                                          \
    u16* _a0 = &As[(dbuf) * 128 + wid * 32][0];                              \
    u16* _a1 = &As[(dbuf) * 128 + wid * 32 + 16][0];                         \
    u16* _b0 = &Bs[(dbuf) * 128 + wid * 32][0];                              \
    u16* _b1 = &Bs[(dbuf) * 128 + wid * 32 + 16][0];                         \
    ASYNC16(ga0 + (k0), _a0);                                                \
    ASYNC16(ga1 + (k0), _a1);                                                \
    ASYNC16(gb0 + (k0), _b0);                                                \
    ASYNC16(gb1 + (k0), _b1);                                                \
  }

  // prologue: stage tiles 0..DEPTH-2
#pragma unroll
  for (int p = 0; p < DEPTH - 1; ++p)
    if (p < nt) STAGE16(p, p << 5);

  for (int t = 0; t < nt; ++t) {
    const int cur = t % DEPTH;
    if (t + DEPTH - 1 < nt) {
      STAGE16((t + DEPTH - 1) % DEPTH, (t + DEPTH - 1) << 5);
      __builtin_amdgcn_sched_barrier(0);
      if constexpr (DEPTH == 3)
        asm volatile("s_waitcnt vmcnt(8)" ::: "memory");
      else
        asm volatile("s_waitcnt vmcnt(4)" ::: "memory");
    } else if (DEPTH == 3 && t + 1 < nt) {
      asm volatile("s_waitcnt vmcnt(4)" ::: "memory");
    } else {
      asm volatile("s_waitcnt vmcnt(0)" ::: "memory");
    }
    __builtin_amdgcn_s_barrier();
    __builtin_amdgcn_sched_barrier(0);
    bfrag af[4], bf4[4];
#pragma unroll
    for (int i = 0; i < 4; i++)
      af[i] = ldfrag(&As[cur * 128 + wr + i * 16 + lr][lq * 8]);
#pragma unroll
    for (int j = 0; j < 4; j++)
      bf4[j] = ldfrag(&Bs[cur * 128 + wc + j * 16 + lr][lq * 8]);
#pragma unroll
    for (int i = 0; i < 4; i++)
#pragma unroll
      for (int j = 0; j < 4; j++)
        acc[i][j] = MFMA(af[i], bf4[j], acc[i][j]);
    asm volatile("s_waitcnt lgkmcnt(0)" ::: "memory");
    __builtin_amdgcn_sched_barrier(0);
    __builtin_amdgcn_s_barrier();
  }
#undef STAGE16
}

// ---------------------------------------------------------------------------
// Fused multi-segment GEMM, bf16 out: C_seg = epi(A @ Wseg^T).
// XCD-swizzled work id; DEPTH templated (QKV=3, FFN1=2 to keep 5 blk/CU).
// ---------------------------------------------------------------------------
struct GSeg { const u16* W; u16* C; int ldc; int nblk; int epi; };
struct GArgs { GSeg s[3]; };

template <int DEPTH>
__global__ __launch_bounds__(256) void gemm128_fused(
    const u16* __restrict__ A, int lda, int K, GArgs args) {
  __shared__ __align__(16) u16 As[DEPTH * 128][32];
  __shared__ __align__(16) u16 Bs[DEPTH * 128][32];
  const int w = xcd_work_id();
  int cb = w % gridDim.x, seg = 0;
  const int by = w / gridDim.x;
  while (cb >= args.s[seg].nblk) { cb -= args.s[seg].nblk; seg++; }
  const GSeg g = args.s[seg];
  const int rowb = by * 128, colb = cb * 128;
  f32x4 acc[4][4] = {};
  gemm128_loop<DEPTH>(A + (size_t)rowb * lda, g.W + (size_t)colb * K, K, lda,
                      K, As, Bs, acc);

  const int lane = threadIdx.x & 63, wid = threadIdx.x >> 6;
  const int lr = lane & 15, lq = lane >> 4;
  const int wr = (wid >> 1) * 64, wc = (wid & 1) * 64;
#pragma unroll
  for (int i = 0; i < 4; i++)
#pragma unroll
    for (int j = 0; j < 4; j++)
#pragma unroll
      for (int r = 0; r < 4; r++) {
        const int row = rowb + wr + i * 16 + lq * 4 + r;
        const int col = colb + wc + j * 16 + lr;
        float v = acc[i][j][r];
        if (g.epi == 2) v = 0.5f * v * (1.0f + erff(v * 0.70710678118654752f));
        else if (g.epi == 3) v = v / (1.0f + __expf(-v));
        g.C[(size_t)row * g.ldc + col] = f2bf(v);
      }
}

// ---------------------------------------------------------------------------
// Wo projection split-K x2: Out += att @ Wo^T partial. Out (d_out) holds x.
// Depth-3 pipeline, XCD-swizzled.
// ---------------------------------------------------------------------------
__global__ __launch_bounds__(256) void gemm128_wo_splitk(
    const u16* __restrict__ A, const u16* __restrict__ W,
    float* __restrict__ Out) {
  __shared__ __align__(16) u16 As[384][32];
  __shared__ __align__(16) u16 Bs[384][32];
  const int w = xcd_work_id();
  const int bx = w % gridDim.x;
  const int by = (w / gridDim.x) % gridDim.y;
  const int z = w / (gridDim.x * gridDim.y);
  const int rowb = by * 128, colb = bx * 128;
  f32x4 acc[4][4] = {};
  gemm128_loop<3>(A + (size_t)rowb * 768 + z * 384,
                  W + (size_t)colb * 768 + z * 384, 384, 768, 768,
                  As, Bs, acc);

  const int lane = threadIdx.x & 63, wid = threadIdx.x >> 6;
  const int lr = lane & 15, lq = lane >> 4;
  const int wr = (wid >> 1) * 64, wc = (wid & 1) * 64;
#pragma unroll
  for (int i = 0; i < 4; i++)
#pragma unroll
    for (int j = 0; j < 4; j++)
#pragma unroll
      for (int r = 0; r < 4; r++) {
        const int row = rowb + wr + i * 16 + lq * 4 + r;
        const int col = colb + wc + j * 16 + lr;
        atomicAdd(&Out[(size_t)row * 768 + col], acc[i][j][r]);
      }
}

// ---------------------------------------------------------------------------
// FFN2 split-K x4: Out += 0.5 * partial. Out holds x1. Depth-3 pipeline,
// XCD-swizzled (x fastest -> col-blocks sharing an A panel colocate).
// ---------------------------------------------------------------------------
__global__ __launch_bounds__(256) void ffn2_splitk(
    const u16* __restrict__ H1, const u16* __restrict__ Ht,
    const u16* __restrict__ Hs, const u16* __restrict__ W2,
    const u16* __restrict__ W2t, const u16* __restrict__ W2s,
    float* __restrict__ Out) {
  __shared__ __align__(16) u16 As[384][32];
  __shared__ __align__(16) u16 Bs[384][32];
  const int w = xcd_work_id();
  const int bx = w % gridDim.x;
  const int by = (w / gridDim.x) % gridDim.y;
  const int z = w / (gridDim.x * gridDim.y);
  const int rowb = by * 128, colb = bx * 128;
  f32x4 acc[4][4] = {};
  if (z == 0)
    gemm128_loop<3>(H1 + (size_t)rowb * 3072, W2 + (size_t)colb * 3072,
                    1536, 3072, 3072, As, Bs, acc);
  else if (z == 1)
    gemm128_loop<3>(H1 + (size_t)rowb * 3072 + 1536,
                    W2 + (size_t)colb * 3072 + 1536,
                    1536, 3072, 3072, As, Bs, acc);
  else if (z == 2)
    gemm128_loop<3>(Ht + (size_t)rowb * 1536, W2t + (size_t)colb * 1536,
                    1536, 1536, 1536, As, Bs, acc);
  else
    gemm128_loop<3>(Hs + (size_t)rowb * 1536, W2s + (size_t)colb * 1536,
                    1536, 1536, 1536, As, Bs, acc);

  const int lane = threadIdx.x & 63, wid = threadIdx.x >> 6;
  const int lr = lane & 15, lq = lane >> 4;
  const int wr = (wid >> 1) * 64, wc = (wid & 1) * 64;
#pragma unroll
  for (int i = 0; i < 4; i++)
#pragma unroll
    for (int j = 0; j < 4; j++)
#pragma unroll
      for (int r = 0; r < 4; r++) {
        const int row = rowb + wr + i * 16 + lq * 4 + r;
        const int col = colb + wc + j * 16 + lr;
        atomicAdd(&Out[(size_t)row * 768 + col], 0.5f * acc[i][j][r]);
      }
}

// ---------------------------------------------------------------------------
// Flash attention producer, causal, KV-split (R13, unchanged). QBLK=64,
// 4 waves. Per bh: 80 chunks; qt<8 writes final; else (O,m,l) partial.
// ---------------------------------------------------------------------------
__global__ __launch_bounds__(256) void flash_attn_k(
    const u16* __restrict__ Qc, const u16* __restrict__ Kb,
    const u16* __restrict__ Vb, u16* __restrict__ O,
    float* __restrict__ Pn, float* __restrict__ Ph) {
  __shared__ __align__(16) u16 Ks[64][40];
  __shared__ __align__(16) u16 Vt[64][72];
  __shared__ __align__(16) u16 Ps[4][16][72];
  const int tid = threadIdx.x, wid = tid >> 6, lane = tid & 63;
  const int lr = lane & 15, lq = lane >> 4;

  // decode blockIdx.x -> (qt, c); qt descending so long chunks launch first
  int bx = blockIdx.x, qt = 0, c = 0;
  for (int q = 31; q >= 0; --q) {
    const int nc = (q < 8) ? 1 : (q / 8 + 1);
    if (bx < nc) { qt = q; c = bx; break; }
    bx -= nc;
  }
  const int nt = qt + 1;
  const int t0 = c * 8;
  const int t1 = (t0 + 8 < nt) ? t0 + 8 : nt;

  const int qb = qt * 64;
  const int bh = blockIdx.y;
  const int b = bh / 12, h = bh % 12;
  const int q0 = qb + wid * 16;
  const size_t base = (size_t)b * 2048 * 768 + h * 64;

  bfrag aq[2];
  aq[0] = ldfrag(Qc + base + (size_t)(q0 + lr) * 768 + lq * 8);
  aq[1] = ldfrag(Qc + base + (size_t)(q0 + lr) * 768 + 32 + lq * 8);

  f32x4 o[4] = {};
  float mrow[4] = {NEG_BIG, NEG_BIG, NEG_BIG, NEG_BIG};
  float lrow[4] = {0.0f, 0.0f, 0.0f, 0.0f};

  const int krow = tid >> 3;        // 0..31
  const int kcol = (tid & 7) * 8;
  const int vkey = tid & 31;
  const int vdg = tid >> 5;         // 0..7

  const u16* kp = Kb + base + (size_t)(t0 * 64 + krow) * 768 + kcol;
  const u16* vp = Vb + base + (size_t)(t0 * 64 + vkey) * 768 + vdg * 8;

  uint4 kv0, kv1, vv0, vv1;
  __builtin_memcpy(&kv0, kp, 16);
  __builtin_memcpy(&kv1, kp + (size_t)32 * 768, 16);
  __builtin_memcpy(&vv0, vp, 16);
  __builtin_memcpy(&vv1, vp + (size_t)32 * 768, 16);

  for (int kt = t0; kt < t1; kt++) {
    __syncthreads();
    __builtin_memcpy(&Ks[krow][kcol], &kv0, 16);
    __builtin_memcpy(&Ks[krow + 32][kcol], &kv1, 16);
    {
      union { uint4 u; u16 s[8]; } a, b2;
      a.u = vv0; b2.u = vv1;
#pragma unroll
      for (int j = 0; j < 8; j++) {
        Vt[vdg * 8 + j][vkey] = a.s[j];
        Vt[vdg * 8 + j][vkey + 32] = b2.s[j];
      }
    }
    __syncthreads();
    if (kt + 1 < t1) {
      const size_t koff = (size_t)(kt + 1 - t0) * 64 * 768;
      __builtin_memcpy(&kv0, kp + koff, 16);
      __builtin_memcpy(&kv1, kp + koff + (size_t)32 * 768, 16);
      __builtin_memcpy(&vv0, vp + koff, 16);
      __builtin_memcpy(&vv1, vp + koff + (size_t)32 * 768, 16);
    }

    const int kbk = kt * 64;
    {
      f32x4 s4[4] = {};
#pragma unroll
      for (int kg = 0; kg < 2; kg++) {
#pragma unroll
        for (int cc = 0; cc < 4; cc++) {
          bfrag bk = ldfrag(&Ks[cc * 16 + lr][kg * 32 + lq * 8]);
          s4[cc] = MFMA(aq[kg], bk, s4[cc]);
        }
      }
#pragma unroll
      for (int r = 0; r < 4; r++) {
        const int q = q0 + lq * 4 + r;
        float v[4];
        float mx = NEG_BIG;
#pragma unroll
        for (int cc = 0; cc < 4; cc++) {
          v[cc] = (kbk + cc * 16 + lr > q) ? NEG_BIG : s4[cc][r];
          mx = fmaxf(mx, v[cc]);
        }
#pragma unroll
        for (int off = 8; off >= 1; off >>= 1)
          mx = fmaxf(mx, __shfl_xor(mx, off, 16));
        const float mn = fmaxf(mrow[r], mx);
        const float alpha = __expf(mrow[r] - mn);
        float sm = 0.0f;
        float p[4];
#pragma unroll
        for (int cc = 0; cc < 4; cc++) {
          p[cc] = __expf(v[cc] - mn);
          sm += p[cc];
        }
#pragma unroll
        for (int off = 8; off >= 1; off >>= 1) sm += __shfl_xor(sm, off, 16);
        lrow[r] = lrow[r] * alpha + sm;
        mrow[r] = mn;
#pragma unroll
        for (int dt = 0; dt < 4; dt++) o[dt][r] *= alpha;
#pragma unroll
        for (int cc = 0; cc < 4; cc++)
          Ps[wid][lq * 4 + r][cc * 16 + lr] = f2bf(p[cc]);
      }
      __threadfence_block();
      bfrag pf0 = ldfrag(&Ps[wid][lr][lq * 8]);
      bfrag pf1 = ldfrag(&Ps[wid][lr][32 + lq * 8]);
#pragma unroll
      for (int dt = 0; dt < 4; dt++) {
        bfrag v0 = ldfrag(&Vt[dt * 16 + lr][lq * 8]);
        bfrag v1 = ldfrag(&Vt[dt * 16 + lr][32 + lq * 8]);
        o[dt] = MFMA(pf0, v0, o[dt]);
        o[dt] = MFMA(pf1, v1, o[dt]);
      }
    }
  }

  if (qt < 8) {
    // final: normalize and write bf16
#pragma unroll
    for (int r = 0; r < 4; r++) {
      const float inv = 1.0f / fmaxf(lrow[r], 1e-30f);
      const int q = q0 + lq * 4 + r;
#pragma unroll
      for (int dt = 0; dt < 4; dt++)
        O[base + (size_t)q * 768 + dt * 16 + lr] = f2bf(o[dt][r] * inv);
    }
  } else {
    // partial: slot s = bh*72 + off(qt) + c
    int off = 0;
    for (int j = 8; j < qt; ++j) off += j / 8 + 1;
    const int s = bh * 72 + off + c;
    float* Op = (s < 1536) ? Pn + (size_t)s * 4096
                           : Ph + (size_t)(s - 1536) * 4096;
    float* lmp = Ph + 786432 + (size_t)s * 128;
#pragma unroll
    for (int r = 0; r < 4; r++) {
      const int row = wid * 16 + lq * 4 + r;
#pragma unroll
      for (int dt = 0; dt < 4; dt++)
        Op[(size_t)row * 64 + dt * 16 + lr] = o[dt][r];
      if (lr == 0) { lmp[row] = mrow[r]; lmp[64 + row] = lrow[r]; }
    }
  }
}

// ---------------------------------------------------------------------------
// Merge partials for qt in [8,32): O = sum_c exp(m_c-m_g)*O_c / l_g.
// grid (24, 24): x = qt-8, y = bh.
// ---------------------------------------------------------------------------
__global__ __launch_bounds__(256) void attn_merge_k(
    const float* __restrict__ Pn, const float* __restrict__ Ph,
    u16* __restrict__ O) {
  const int qt = 8 + blockIdx.x;
  const int bh = blockIdx.y;
  const int b = bh / 12, h = bh % 12;
  const int nc = qt / 8 + 1;
  int off = 0;
  for (int j = 8; j < qt; ++j) off += j / 8 + 1;
  const int s0 = bh * 72 + off;
  const int row = threadIdx.x >> 2;
  const int c0 = (threadIdx.x & 3) * 16;
  const float* lmb = Ph + 786432;

  float mg = NEG_BIG;
  for (int cc = 0; cc < nc; ++cc)
    mg = fmaxf(mg, lmb[(size_t)(s0 + cc) * 128 + row]);

  float acc[16];
#pragma unroll
  for (int j = 0; j < 16; j++) acc[j] = 0.0f;
  float lg = 0.0f;
  for (int cc = 0; cc < nc; ++cc) {
    const int s = s0 + cc;
    const float mcv = lmb[(size_t)s * 128 + row];
    const float coef = __expf(mcv - mg);
    lg += coef * lmb[(size_t)s * 128 + 64 + row];
    const float* Op = (s < 1536) ? Pn + (size_t)s * 4096
                                 : Ph + (size_t)(s - 1536) * 4096;
    const float* rp = Op + (size_t)row * 64 + c0;
#pragma unroll
    for (int g = 0; g < 4; g++) {
      float4 v;
      __builtin_memcpy(&v, rp + g * 4, 16);
      acc[g * 4 + 0] += coef * v.x;
      acc[g * 4 + 1] += coef * v.y;
      acc[g * 4 + 2] += coef * v.z;
      acc[g * 4 + 3] += coef * v.w;
    }
  }
  const float inv = 1.0f / fmaxf(lg, 1e-30f);
  const int q = qt * 64 + row;
  const size_t ob = (size_t)b * 2048 * 768 + h * 64 + (size_t)q * 768 + c0;
#pragma unroll
  for (int j = 0; j < 16; j++) O[ob + j] = f2bf(acc[j] * inv);
}

// ---------------------------------------------------------------------------
extern "C" void kernel_launch(void* const* d_in, const int* in_sizes, int n_in,
                              void* d_out, int out_size, void* d_ws,
                              size_t ws_size, hipStream_t stream) {
  (void)in_sizes; (void)n_in; (void)out_size; (void)ws_size;
  const float* x = (const float*)d_in[0];
  const void* mask = d_in[2];

  char* ws = (char*)d_ws;
  u16* Wb  = (u16*)(ws);                        // bf16 arena, 23599104 B
  u16* n1h = (u16*)(ws + 23599104);             // 4096x3072 bf16 (h1 / attn partials)
  u16* Qb  = (u16*)(ws + 48764928);             // 4096x768 (later n2)
  u16* Kb2 = (u16*)(ws + 55056384);             // 4096x768
  u16* Vb2 = (u16*)(ws + 61347840);             // 4096x768
  u16* att = (u16*)(ws + 67639296);             // 4096x768 att, later ht (x1536)
  u16* hs  = (u16*)(ws + 80222208);             // 4096x1536 (attn partial spill)
  float* mfl = (float*)(ws + 92805120);         // 768 floats
  float* x1 = (float*)d_out;                    // x / x1 fp32 live in d_out
  float* Pn = (float*)n1h;                      // 1536 partial slots x 4096 f32
  float* Ph = (float*)hs;                       // 192 slots + m/l at +786432 f32

  u16* Wq = Wb + 0,        *Wk = Wb + 589824,   *Wv = Wb + 1179648;
  u16* Wo = Wb + 1769472,  *w1 = Wb + 2359296,  *w1t = Wb + 4718592;
  u16* w1s = Wb + 5898240, *w2 = Wb + 7077888,  *w2t = Wb + 9437184;
  u16* w2s = Wb + 10616832;
  u16* n1w = Wb + 11796480, *n1b = Wb + 11797248;
  u16* n2w = Wb + 11798016, *n2b = Wb + 11798784;

  Segs sg;
  const int srcidx[14] = {3, 4, 5, 6, 7, 9, 11, 8, 10, 12, 13, 14, 15, 16};
  const int offs[14] = {0, 589824, 1179648, 1769472, 2359296, 4718592,
                        5898240, 7077888, 9437184, 10616832,
                        11796480, 11797248, 11798016, 11798784};
  const int ns[14] = {589824, 589824, 589824, 589824, 2359296, 1179648,
                      1179648, 2359296, 1179648, 1179648, 768, 768, 768, 768};
  const int mms[14] = {0, 0, 0, 0, 0, 1, 2, 0, 0, 0, 0, 0, 0, 0};
  for (int i = 0; i < 14; i++) {
    sg.src[i] = d_in[srcidx[i]];
    sg.off[i] = offs[i];
    sg.n[i] = ns[i];
    sg.mmode[i] = mms[i];
  }

  mask_conv_k<<<1, 256, 0, stream>>>(mask, mfl);
  convert_k<<<dim3(2304, 14), 256, 0, stream>>>(sg, Wb, mfl);

  // n1 = mink_norm(x); also seed d_out with x (residual base for Wo atomics)
  mink_norm_k<<<4096, 256, 0, stream>>>(x, mfl, n1w, n1b, n1h, x1);

  // Q,K,V fused (N=2304), XCD-swizzled, depth-3
  GArgs qkv;
  qkv.s[0] = {Wq, Qb, 768, 6, 0};
  qkv.s[1] = {Wk, Kb2, 768, 6, 0};
  qkv.s[2] = {Wv, Vb2, 768, 6, 0};
  gemm128_fused<3><<<dim3(18, 32), 256, 0, stream>>>(n1h, 768, 768, qkv);

  qcorr_k<<<12288, 256, 0, stream>>>(Qb, mfl);

  // flash attention: 80 chunks/bh, partials into Pn/Ph, then merge
  flash_attn_k<<<dim3(80, 24), 256, 0, stream>>>(Qb, Kb2, Vb2, att, Pn, Ph);
  attn_merge_k<<<dim3(24, 24), 256, 0, stream>>>(Pn, Ph, att);

  // x1 = x + att @ Wo^T  (split-K x2 atomic into d_out holding x), depth-3
  gemm128_wo_splitk<<<dim3(6, 32, 2), 256, 0, stream>>>(att, Wo, x1);

  // n2 = mink_norm(x1) -> Qb (mask folded into FFN1 weights)
  mink_norm_k<<<4096, 256, 0, stream>>>(x1, mfl, n2w, n2b, Qb, nullptr);

  // FFN1 fused (N=6144): h1 = gelu(n2@w1^T), ht = silu(n2@w1t_m^T),
  // hs = gelu(n2@w1s_m^T), XCD-swizzled, depth-2 (keeps 5 blocks/CU)
  GArgs ffn1;
  ffn1.s[0] = {w1, n1h, 3072, 24, 2};
  ffn1.s[1] = {w1t, att, 1536, 12, 3};
  ffn1.s[2] = {w1s, hs, 1536, 12, 2};
  gemm128_fused<2><<<dim3(48, 32), 256, 0, stream>>>(Qb, 768, 768, ffn1);

  // out = x1 + 0.5*(h1@w2^T + ht@w2_t^T + hs@w2_s^T), split-K x4, depth-3
  ffn2_splitk<<<dim3(6, 32, 4), 256, 0, stream>>>(n1h, att, hs, w2, w2t, w2s,
                                                  (float*)d_out);
}

// Round 9
// 438.247 us; speedup vs baseline: 1.0122x; 1.0122x over previous
//
#include <hip/hip_runtime.h>

// LorentzBlock: B=2, L=2048, D=768, H=12, DH=64, DFF=3072
// R19: ffn2 atomics eliminated. Evidence: ffn2 invariant 86-90us across
// pipeline depth 1/2/3 but scaled with atomic count (R15 x8: 124us);
// WRITE_SIZE == atomic bytes exactly (device-scope fp32 atomics serialize
// at the memory-side coherence point, ~3us/M). New split:
//   z=0: h1@w2 full K=3072 -> d_out += 0.5*P (plain RMW, single writer)
//   z=1: ht@w2t -> fp32 partial in dead Qb+Kb2 (12.6MB)
//   z=2: hs@w2s -> bf16 partial in dead Vb2 (6.3MB)
// + ffn2_reduce. Balanced XCD swizzle (z fastest: 24 long + 48 short
// blocks per XCD chunk). Depth-3 reverted (R18: null on ffn2, -19us total).
// Keeps R17 depth-2 counted-vmcnt loop + XCD swizzle + R13 flash-decode.

typedef unsigned short u16;
typedef __bf16 bfrag __attribute__((ext_vector_type(8)));
typedef float f32x4 __attribute__((ext_vector_type(4)));

#define MFMA(a, b, c) __builtin_amdgcn_mfma_f32_16x16x32_bf16(a, b, c, 0, 0, 0)
#define NEG_BIG (-30000.0f)
#define ASYNC16(g, l)                                                        \
  __builtin_amdgcn_global_load_lds(                                          \
      (const __attribute__((address_space(1))) unsigned int*)(g),            \
      (__attribute__((address_space(3))) unsigned int*)(l), 16, 0, 0)

__device__ __forceinline__ float bf2f(u16 u) {
  unsigned int v = ((unsigned int)u) << 16;
  float f; __builtin_memcpy(&f, &v, 4); return f;
}
__device__ __forceinline__ u16 f2bf(float f) {
  unsigned int v; __builtin_memcpy(&v, &f, 4);
  v += 0x7fffu + ((v >> 16) & 1u);   // RNE
  return (u16)(v >> 16);
}
__device__ __forceinline__ bfrag ldfrag(const u16* p) {
  bfrag v; __builtin_memcpy(&v, p, 16); return v;
}

// XCD-chunked bijective swizzle of the linear workgroup id. Requires
// nwg % 8 == 0 (all call sites comply); identity fallback otherwise.
__device__ __forceinline__ int xcd_work_id() {
  const int nx = gridDim.x, ny = gridDim.y;
  const int nwg = nx * ny * gridDim.z;
  const int orig = blockIdx.x + nx * (blockIdx.y + ny * blockIdx.z);
  if (nwg & 7) return orig;
  return (orig & 7) * (nwg >> 3) + (orig >> 3);
}

// ---------------------------------------------------------------------------
// Mask canonicalization -> float[768].
// ---------------------------------------------------------------------------
__global__ __launch_bounds__(256) void mask_conv_k(const void* __restrict__ mask,
                                                   float* __restrict__ mfl) {
  __shared__ int msh;
  if (threadIdx.x == 0) msh = 0;
  __syncthreads();
  const unsigned int* w = (const unsigned int*)mask;
  if (threadIdx.x < 192) {
    const unsigned int v = w[threadIdx.x];
    if ((v & 0xFFFFu) == 0x3F80u) atomicOr(&msh, 4);
    else if (v == 0x3F800000u) atomicOr(&msh, 2);
    else if (v >= 2u) atomicOr(&msh, 1);
  }
  __syncthreads();
  const int m = msh;
  const int mode = (m & 4) ? 3 : (m & 2) ? 2 : (m & 1) ? 1 : 0;
  for (int i = threadIdx.x; i < 768; i += 256) {
    int b;
    if (mode == 3) b = ((const u16*)mask)[i] != 0;
    else if (mode == 2) b = ((const float*)mask)[i] != 0.0f;
    else if (mode == 1) b = ((const unsigned char*)mask)[i] != 0;
    else b = ((const int*)mask)[i] != 0;
    mfl[i] = (float)b;
  }
}

// ---------------------------------------------------------------------------
// Convert fp32 weight segments -> bf16 arena. mmode: 0 none, 1 *m[k],
// 2 *(1-m[k]) with k = i % 768 (mask fold for w1_t / w1_s).
// ---------------------------------------------------------------------------
struct Segs {
  const void* src[14];
  int off[14];
  int n[14];
  int mmode[14];
};

__global__ __launch_bounds__(256) void convert_k(Segs segs, u16* __restrict__ dstb,
                                                 const float* __restrict__ mfl) {
  const int seg = blockIdx.y;
  const int n = segs.n[seg];
  const int mm = segs.mmode[seg];
  u16* dst = dstb + segs.off[seg];
  const float* src = (const float*)segs.src[seg];
  for (int i = (blockIdx.x * 256 + threadIdx.x) * 4; i < n; i += gridDim.x * 1024) {
    float4 v;
    __builtin_memcpy(&v, src + i, 16);
    if (mm) {
      const int k = i % 768;
      float m0 = mfl[k], m1 = mfl[k + 1], m2 = mfl[k + 2], m3 = mfl[k + 3];
      if (mm == 2) { m0 = 1.f - m0; m1 = 1.f - m1; m2 = 1.f - m2; m3 = 1.f - m3; }
      v.x *= m0; v.y *= m1; v.z *= m2; v.w *= m3;
    }
    dst[i] = f2bf(v.x); dst[i + 1] = f2bf(v.y);
    dst[i + 2] = f2bf(v.z); dst[i + 3] = f2bf(v.w);
  }
}

// ---------------------------------------------------------------------------
// Minkowski LayerNorm. fp32 input, bf16 output. Optionally copies the raw
// input row to Xcopy (fp32) -- seeds d_out with x for the Wo split-K atomics.
// ---------------------------------------------------------------------------
__global__ __launch_bounds__(256) void mink_norm_k(
    const float* __restrict__ X, const float* __restrict__ mf,
    const u16* __restrict__ w, const u16* __restrict__ bias,
    u16* __restrict__ Y, float* __restrict__ Xcopy) {
  __shared__ float red[8];
  const int row = blockIdx.x, tid = threadIdx.x;
  const int wid = tid >> 6, lane = tid & 63;
  const size_t roff = (size_t)row * 768;

  float xv[3], mv[3];
  int idx[3];
#pragma unroll
  for (int i = 0; i < 3; i++) {
    idx[i] = tid + i * 256;
    xv[i] = X[roff + idx[i]];
    mv[i] = mf[idx[i]];
  }
  if (Xcopy) {
#pragma unroll
    for (int i = 0; i < 3; i++) Xcopy[roff + idx[i]] = xv[i];
  }
  float s = xv[0] + xv[1] + xv[2];
#pragma unroll
  for (int o = 32; o >= 1; o >>= 1) s += __shfl_xor(s, o, 64);
  if (lane == 0) red[wid] = s;
  __syncthreads();
  const float mean = (red[0] + red[1] + red[2] + red[3]) * (1.0f / 768.0f);
  __syncthreads();

  float xc[3], ss = 0.0f, sm = 0.0f;
#pragma unroll
  for (int i = 0; i < 3; i++) {
    xc[i] = xv[i] - mean;
    ss += xc[i] * xc[i];
    sm += xc[i] * xc[i] * mv[i];
  }
#pragma unroll
  for (int o = 32; o >= 1; o >>= 1) {
    ss += __shfl_xor(ss, o, 64);
    sm += __shfl_xor(sm, o, 64);
  }
  if (lane == 0) { red[wid] = ss; red[4 + wid] = sm; }
  __syncthreads();
  const float sumsq = red[0] + red[1] + red[2] + red[3];
  const float summ = red[4] + red[5] + red[6] + red[7];
  const float var = sumsq * (1.0f / 768.0f);
  const float eta = sumsq - 2.0f * summ;
  const float rs = 1.0f / sqrtf(var + 1e-5f);
  const float re = 1.0f / sqrtf(fabsf(eta) + 1e-5f);

#pragma unroll
  for (int i = 0; i < 3; i++) {
    const float xn = xc[i] * 0.5f * (rs + re);
    Y[roff + idx[i]] = f2bf(bf2f(w[idx[i]]) * xn + bf2f(bias[idx[i]]));
  }
}

// ---------------------------------------------------------------------------
// Q Lorentz correction, in place. 4 rows per block (one per wave).
// ---------------------------------------------------------------------------
__global__ __launch_bounds__(256) void qcorr_k(u16* __restrict__ Q,
                                               const float* __restrict__ mf) {
  const int idx = blockIdx.x * 4 + (threadIdx.x >> 6);  // (b*2048+l)*12+h
  const int t = threadIdx.x & 63;
  const int h = idx % 12;
  const int bl = idx / 12;
  const size_t off = (size_t)bl * 768 + h * 64 + t;
  const float q = bf2f(Q[off]);
  const float m = mf[h * 64 + t];
  float q2 = q * q, qm2 = q * q * m;
#pragma unroll
  for (int o = 32; o >= 1; o >>= 1) {
    q2 += __shfl_xor(q2, o, 64);
    qm2 += __shfl_xor(qm2, o, 64);
  }
  const float qn = sqrtf(q2), qtn = sqrtf(qm2);
  const float sf = (qtn > 1e-6f) ? qn / fmaxf(qtn, 1e-8f) : 0.0f;
  Q[off] = f2bf(q * (1.0f - 0.5f * sf * m) * 0.125f);
}

// ---------------------------------------------------------------------------
// 128x128 MFMA GEMM core, counted-vmcnt 2-phase double-buffered (R16/R17).
// As/Bs are [256][32]: buffer d = rows [d*128, d*128+128). Per K-iter:
//   STAGE(tile t+1 -> buf^1); vmcnt(4); s_barrier; ds_read+MFMA buf[cur];
//   lgkmcnt(0)+sched_barrier; s_barrier. Never vmcnt(0) in-loop (T4).
// ---------------------------------------------------------------------------
__device__ __forceinline__ void gemm128_loop(
    const u16* __restrict__ Ab, const u16* __restrict__ Wb2,
    int K, int lda, int ldb, u16 (*As)[32], u16 (*Bs)[32], f32x4 acc[4][4]) {
  const int tid = threadIdx.x;
  const int wid = tid >> 6, lane = tid & 63;
  const int lr = lane & 15, lq = lane >> 4;
  const int srow = wid * 32 + (lane >> 2);
  const int scol = (lane & 3) * 8;
  const u16* ga0 = Ab + (size_t)srow * lda + scol;
  const u16* ga1 = Ab + (size_t)(srow + 16) * lda + scol;
  const u16* gb0 = Wb2 + (size_t)srow * ldb + scol;
  const u16* gb1 = Wb2 + (size_t)(srow + 16) * ldb + scol;
  const int wr = (wid >> 1) * 64, wc = (wid & 1) * 64;
  const int nt = K >> 5;

#define STAGE16(dbuf, k0)                                                    \
  {                                                                          \
    u16* _a0 = &As[(dbuf) * 128 + wid * 32][0];                              \
    u16* _a1 = &As[(dbuf) * 128 + wid * 32 + 16][0];                         \
    u16* _b0 = &Bs[(dbuf) * 128 + wid * 32][0];                              \
    u16* _b1 = &Bs[(dbuf) * 128 + wid * 32 + 16][0];                         \
    ASYNC16(ga0 + (k0), _a0);                                                \
    ASYNC16(ga1 + (k0), _a1);                                                \
    ASYNC16(gb0 + (k0), _b0);                                                \
    ASYNC16(gb1 + (k0), _b1);                                                \
  }

  STAGE16(0, 0);
  for (int t = 0; t < nt; ++t) {
    const int cur = t & 1;
    if (t + 1 < nt) {
      STAGE16(cur ^ 1, (t + 1) << 5);
      __builtin_amdgcn_sched_barrier(0);
      asm volatile("s_waitcnt vmcnt(4)" ::: "memory");
    } else {
      asm volatile("s_waitcnt vmcnt(0)" ::: "memory");
    }
    __builtin_amdgcn_s_barrier();
    __builtin_amdgcn_sched_barrier(0);
    bfrag af[4], bf4[4];
#pragma unroll
    for (int i = 0; i < 4; i++)
      af[i] = ldfrag(&As[cur * 128 + wr + i * 16 + lr][lq * 8]);
#pragma unroll
    for (int j = 0; j < 4; j++)
      bf4[j] = ldfrag(&Bs[cur * 128 + wc + j * 16 + lr][lq * 8]);
#pragma unroll
    for (int i = 0; i < 4; i++)
#pragma unroll
      for (int j = 0; j < 4; j++)
        acc[i][j] = MFMA(af[i], bf4[j], acc[i][j]);
    asm volatile("s_waitcnt lgkmcnt(0)" ::: "memory");
    __builtin_amdgcn_sched_barrier(0);
    __builtin_amdgcn_s_barrier();
  }
#undef STAGE16
}

// ---------------------------------------------------------------------------
// Fused multi-segment GEMM, bf16 out: C_seg = epi(A @ Wseg^T).
// XCD-swizzled work id.
// ---------------------------------------------------------------------------
struct GSeg { const u16* W; u16* C; int ldc; int nblk; int epi; };
struct GArgs { GSeg s[3]; };

__global__ __launch_bounds__(256) void gemm128_fused(
    const u16* __restrict__ A, int lda, int K, GArgs args) {
  __shared__ __align__(16) u16 As[256][32];
  __shared__ __align__(16) u16 Bs[256][32];
  const int w = xcd_work_id();
  int cb = w % gridDim.x, seg = 0;
  const int by = w / gridDim.x;
  while (cb >= args.s[seg].nblk) { cb -= args.s[seg].nblk; seg++; }
  const GSeg g = args.s[seg];
  const int rowb = by * 128, colb = cb * 128;
  f32x4 acc[4][4] = {};
  gemm128_loop(A + (size_t)rowb * lda, g.W + (size_t)colb * K, K, lda, K,
               As, Bs, acc);

  const int lane = threadIdx.x & 63, wid = threadIdx.x >> 6;
  const int lr = lane & 15, lq = lane >> 4;
  const int wr = (wid >> 1) * 64, wc = (wid & 1) * 64;
#pragma unroll
  for (int i = 0; i < 4; i++)
#pragma unroll
    for (int j = 0; j < 4; j++)
#pragma unroll
      for (int r = 0; r < 4; r++) {
        const int row = rowb + wr + i * 16 + lq * 4 + r;
        const int col = colb + wc + j * 16 + lr;
        float v = acc[i][j][r];
        if (g.epi == 2) v = 0.5f * v * (1.0f + erff(v * 0.70710678118654752f));
        else if (g.epi == 3) v = v / (1.0f + __expf(-v));
        g.C[(size_t)row * g.ldc + col] = f2bf(v);
      }
}

// ---------------------------------------------------------------------------
// Wo projection split-K x2: Out += att @ Wo^T partial. Out (d_out) holds x.
// Depth-2 pipeline, XCD-swizzled. (6.3M atomics -- next candidate if the
// ffn2 atomic theory confirms.)
// ---------------------------------------------------------------------------
__global__ __launch_bounds__(256) void gemm128_wo_splitk(
    const u16* __restrict__ A, const u16* __restrict__ W,
    float* __restrict__ Out) {
  __shared__ __align__(16) u16 As[256][32];
  __shared__ __align__(16) u16 Bs[256][32];
  const int w = xcd_work_id();
  const int bx = w % gridDim.x;
  const int by = (w / gridDim.x) % gridDim.y;
  const int z = w / (gridDim.x * gridDim.y);
  const int rowb = by * 128, colb = bx * 128;
  f32x4 acc[4][4] = {};
  gemm128_loop(A + (size_t)rowb * 768 + z * 384,
               W + (size_t)colb * 768 + z * 384, 384, 768, 768, As, Bs, acc);

  const int lane = threadIdx.x & 63, wid = threadIdx.x >> 6;
  const int lr = lane & 15, lq = lane >> 4;
  const int wr = (wid >> 1) * 64, wc = (wid & 1) * 64;
#pragma unroll
  for (int i = 0; i < 4; i++)
#pragma unroll
    for (int j = 0; j < 4; j++)
#pragma unroll
      for (int r = 0; r < 4; r++) {
        const int row = rowb + wr + i * 16 + lq * 4 + r;
        const int col = colb + wc + j * 16 + lr;
        atomicAdd(&Out[(size_t)row * 768 + col], acc[i][j][r]);
      }
}

// ---------------------------------------------------------------------------
// FFN2, 3-way owned-output split (NO atomics):
//   z=0: P = h1@w2 (K=3072)  -> Out += 0.5*P (plain RMW; Out holds x1)
//   z=1: P = ht@w2t (K=1536) -> Pt fp32 partial (raw P)
//   z=2: P = hs@w2s (K=1536) -> Ps16 bf16 partial (raw P)
// Balanced XCD swizzle: z fastest in work id -> each XCD chunk of 72 = 24
// long + 48 short blocks (96 work-units each) + 4 contiguous row panels.
// ---------------------------------------------------------------------------
__global__ __launch_bounds__(256) void ffn2_split3(
    const u16* __restrict__ H1, const u16* __restrict__ Ht,
    const u16* __restrict__ Hs, const u16* __restrict__ W2,
    const u16* __restrict__ W2t, const u16* __restrict__ W2s,
    float* __restrict__ Out, float* __restrict__ Pt, u16* __restrict__ Ps16) {
  __shared__ __align__(16) u16 As[256][32];
  __shared__ __align__(16) u16 Bs[256][32];
  const int orig = blockIdx.x + 6 * (blockIdx.y + 32 * blockIdx.z);  // 0..575
  const int w = (orig & 7) * 72 + (orig >> 3);
  const int z = w % 3;
  const int bx = (w / 3) % 6;
  const int by = w / 18;
  const int rowb = by * 128, colb = bx * 128;
  f32x4 acc[4][4] = {};
  if (z == 0)
    gemm128_loop(H1 + (size_t)rowb * 3072, W2 + (size_t)colb * 3072,
                 3072, 3072, 3072, As, Bs, acc);
  else if (z == 1)
    gemm128_loop(Ht + (size_t)rowb * 1536, W2t + (size_t)colb * 1536,
                 1536, 1536, 1536, As, Bs, acc);
  else
    gemm128_loop(Hs + (size_t)rowb * 1536, W2s + (size_t)colb * 1536,
                 1536, 1536, 1536, As, Bs, acc);

  const int lane = threadIdx.x & 63, wid = threadIdx.x >> 6;
  const int lr = lane & 15, lq = lane >> 4;
  const int wr = (wid >> 1) * 64, wc = (wid & 1) * 64;
#pragma unroll
  for (int i = 0; i < 4; i++)
#pragma unroll
    for (int j = 0; j < 4; j++)
#pragma unroll
      for (int r = 0; r < 4; r++) {
        const int row = rowb + wr + i * 16 + lq * 4 + r;
        const int col = colb + wc + j * 16 + lr;
        const size_t o = (size_t)row * 768 + col;
        if (z == 0) Out[o] = Out[o] + 0.5f * acc[i][j][r];
        else if (z == 1) Pt[o] = acc[i][j][r];
        else Ps16[o] = f2bf(acc[i][j][r]);
      }
}

// ---------------------------------------------------------------------------
// FFN2 reduce: Out += 0.5*(Pt + bf2f(Ps16)). 3072 blocks x 256 thr x 4 elem.
// ---------------------------------------------------------------------------
__global__ __launch_bounds__(256) void ffn2_reduce(
    float* __restrict__ Out, const float* __restrict__ Pt,
    const u16* __restrict__ Ps16) {
  const int i = (blockIdx.x * 256 + threadIdx.x) * 4;
  float4 o, t;
  __builtin_memcpy(&o, Out + i, 16);
  __builtin_memcpy(&t, Pt + i, 16);
  ushort4 s;
  __builtin_memcpy(&s, Ps16 + i, 8);
  o.x += 0.5f * (t.x + bf2f(s.x));
  o.y += 0.5f * (t.y + bf2f(s.y));
  o.z += 0.5f * (t.z + bf2f(s.z));
  o.w += 0.5f * (t.w + bf2f(s.w));
  __builtin_memcpy(Out + i, &o, 16);
}

// ---------------------------------------------------------------------------
// Flash attention producer, causal, KV-split (R13, unchanged). QBLK=64,
// 4 waves. Per bh: 80 chunks; qt<8 writes final; else (O,m,l) partial.
// ---------------------------------------------------------------------------
__global__ __launch_bounds__(256) void flash_attn_k(
    const u16* __restrict__ Qc, const u16* __restrict__ Kb,
    const u16* __restrict__ Vb, u16* __restrict__ O,
    float* __restrict__ Pn, float* __restrict__ Ph) {
  __shared__ __align__(16) u16 Ks[64][40];
  __shared__ __align__(16) u16 Vt[64][72];
  __shared__ __align__(16) u16 Ps[4][16][72];
  const int tid = threadIdx.x, wid = tid >> 6, lane = tid & 63;
  const int lr = lane & 15, lq = lane >> 4;

  // decode blockIdx.x -> (qt, c); qt descending so long chunks launch first
  int bx = blockIdx.x, qt = 0, c = 0;
  for (int q = 31; q >= 0; --q) {
    const int nc = (q < 8) ? 1 : (q / 8 + 1);
    if (bx < nc) { qt = q; c = bx; break; }
    bx -= nc;
  }
  const int nt = qt + 1;
  const int t0 = c * 8;
  const int t1 = (t0 + 8 < nt) ? t0 + 8 : nt;

  const int qb = qt * 64;
  const int bh = blockIdx.y;
  const int b = bh / 12, h = bh % 12;
  const int q0 = qb + wid * 16;
  const size_t base = (size_t)b * 2048 * 768 + h * 64;

  bfrag aq[2];
  aq[0] = ldfrag(Qc + base + (size_t)(q0 + lr) * 768 + lq * 8);
  aq[1] = ldfrag(Qc + base + (size_t)(q0 + lr) * 768 + 32 + lq * 8);

  f32x4 o[4] = {};
  float mrow[4] = {NEG_BIG, NEG_BIG, NEG_BIG, NEG_BIG};
  float lrow[4] = {0.0f, 0.0f, 0.0f, 0.0f};

  const int krow = tid >> 3;        // 0..31
  const int kcol = (tid & 7) * 8;
  const int vkey = tid & 31;
  const int vdg = tid >> 5;         // 0..7

  const u16* kp = Kb + base + (size_t)(t0 * 64 + krow) * 768 + kcol;
  const u16* vp = Vb + base + (size_t)(t0 * 64 + vkey) * 768 + vdg * 8;

  uint4 kv0, kv1, vv0, vv1;
  __builtin_memcpy(&kv0, kp, 16);
  __builtin_memcpy(&kv1, kp + (size_t)32 * 768, 16);
  __builtin_memcpy(&vv0, vp, 16);
  __builtin_memcpy(&vv1, vp + (size_t)32 * 768, 16);

  for (int kt = t0; kt < t1; kt++) {
    __syncthreads();
    __builtin_memcpy(&Ks[krow][kcol], &kv0, 16);
    __builtin_memcpy(&Ks[krow + 32][kcol], &kv1, 16);
    {
      union { uint4 u; u16 s[8]; } a, b2;
      a.u = vv0; b2.u = vv1;
#pragma unroll
      for (int j = 0; j < 8; j++) {
        Vt[vdg * 8 + j][vkey] = a.s[j];
        Vt[vdg * 8 + j][vkey + 32] = b2.s[j];
      }
    }
    __syncthreads();
    if (kt + 1 < t1) {
      const size_t koff = (size_t)(kt + 1 - t0) * 64 * 768;
      __builtin_memcpy(&kv0, kp + koff, 16);
      __builtin_memcpy(&kv1, kp + koff + (size_t)32 * 768, 16);
      __builtin_memcpy(&vv0, vp + koff, 16);
      __builtin_memcpy(&vv1, vp + koff + (size_t)32 * 768, 16);
    }

    const int kbk = kt * 64;
    {
      f32x4 s4[4] = {};
#pragma unroll
      for (int kg = 0; kg < 2; kg++) {
#pragma unroll
        for (int cc = 0; cc < 4; cc++) {
          bfrag bk = ldfrag(&Ks[cc * 16 + lr][kg * 32 + lq * 8]);
          s4[cc] = MFMA(aq[kg], bk, s4[cc]);
        }
      }
#pragma unroll
      for (int r = 0; r < 4; r++) {
        const int q = q0 + lq * 4 + r;
        float v[4];
        float mx = NEG_BIG;
#pragma unroll
        for (int cc = 0; cc < 4; cc++) {
          v[cc] = (kbk + cc * 16 + lr > q) ? NEG_BIG : s4[cc][r];
          mx = fmaxf(mx, v[cc]);
        }
#pragma unroll
        for (int off = 8; off >= 1; off >>= 1)
          mx = fmaxf(mx, __shfl_xor(mx, off, 16));
        const float mn = fmaxf(mrow[r], mx);
        const float alpha = __expf(mrow[r] - mn);
        float sm = 0.0f;
        float p[4];
#pragma unroll
        for (int cc = 0; cc < 4; cc++) {
          p[cc] = __expf(v[cc] - mn);
          sm += p[cc];
        }
#pragma unroll
        for (int off = 8; off >= 1; off >>= 1) sm += __shfl_xor(sm, off, 16);
        lrow[r] = lrow[r] * alpha + sm;
        mrow[r] = mn;
#pragma unroll
        for (int dt = 0; dt < 4; dt++) o[dt][r] *= alpha;
#pragma unroll
        for (int cc = 0; cc < 4; cc++)
          Ps[wid][lq * 4 + r][cc * 16 + lr] = f2bf(p[cc]);
      }
      __threadfence_block();
      bfrag pf0 = ldfrag(&Ps[wid][lr][lq * 8]);
      bfrag pf1 = ldfrag(&Ps[wid][lr][32 + lq * 8]);
#pragma unroll
      for (int dt = 0; dt < 4; dt++) {
        bfrag v0 = ldfrag(&Vt[dt * 16 + lr][lq * 8]);
        bfrag v1 = ldfrag(&Vt[dt * 16 + lr][32 + lq * 8]);
        o[dt] = MFMA(pf0, v0, o[dt]);
        o[dt] = MFMA(pf1, v1, o[dt]);
      }
    }
  }

  if (qt < 8) {
    // final: normalize and write bf16
#pragma unroll
    for (int r = 0; r < 4; r++) {
      const float inv = 1.0f / fmaxf(lrow[r], 1e-30f);
      const int q = q0 + lq * 4 + r;
#pragma unroll
      for (int dt = 0; dt < 4; dt++)
        O[base + (size_t)q * 768 + dt * 16 + lr] = f2bf(o[dt][r] * inv);
    }
  } else {
    // partial: slot s = bh*72 + off(qt) + c
    int off = 0;
    for (int j = 8; j < qt; ++j) off += j / 8 + 1;
    const int s = bh * 72 + off + c;
    float* Op = (s < 1536) ? Pn + (size_t)s * 4096
                           : Ph + (size_t)(s - 1536) * 4096;
    float* lmp = Ph + 786432 + (size_t)s * 128;
#pragma unroll
    for (int r = 0; r < 4; r++) {
      const int row = wid * 16 + lq * 4 + r;
#pragma unroll
      for (int dt = 0; dt < 4; dt++)
        Op[(size_t)row * 64 + dt * 16 + lr] = o[dt][r];
      if (lr == 0) { lmp[row] = mrow[r]; lmp[64 + row] = lrow[r]; }
    }
  }
}

// ---------------------------------------------------------------------------
// Merge partials for qt in [8,32): O = sum_c exp(m_c-m_g)*O_c / l_g.
// grid (24, 24): x = qt-8, y = bh.
// ---------------------------------------------------------------------------
__global__ __launch_bounds__(256) void attn_merge_k(
    const float* __restrict__ Pn, const float* __restrict__ Ph,
    u16* __restrict__ O) {
  const int qt = 8 + blockIdx.x;
  const int bh = blockIdx.y;
  const int b = bh / 12, h = bh % 12;
  const int nc = qt / 8 + 1;
  int off = 0;
  for (int j = 8; j < qt; ++j) off += j / 8 + 1;
  const int s0 = bh * 72 + off;
  const int row = threadIdx.x >> 2;
  const int c0 = (threadIdx.x & 3) * 16;
  const float* lmb = Ph + 786432;

  float mg = NEG_BIG;
  for (int cc = 0; cc < nc; ++cc)
    mg = fmaxf(mg, lmb[(size_t)(s0 + cc) * 128 + row]);

  float acc[16];
#pragma unroll
  for (int j = 0; j < 16; j++) acc[j] = 0.0f;
  float lg = 0.0f;
  for (int cc = 0; cc < nc; ++cc) {
    const int s = s0 + cc;
    const float mcv = lmb[(size_t)s * 128 + row];
    const float coef = __expf(mcv - mg);
    lg += coef * lmb[(size_t)s * 128 + 64 + row];
    const float* Op = (s < 1536) ? Pn + (size_t)s * 4096
                                 : Ph + (size_t)(s - 1536) * 4096;
    const float* rp = Op + (size_t)row * 64 + c0;
#pragma unroll
    for (int g = 0; g < 4; g++) {
      float4 v;
      __builtin_memcpy(&v, rp + g * 4, 16);
      acc[g * 4 + 0] += coef * v.x;
      acc[g * 4 + 1] += coef * v.y;
      acc[g * 4 + 2] += coef * v.z;
      acc[g * 4 + 3] += coef * v.w;
    }
  }
  const float inv = 1.0f / fmaxf(lg, 1e-30f);
  const int q = qt * 64 + row;
  const size_t ob = (size_t)b * 2048 * 768 + h * 64 + (size_t)q * 768 + c0;
#pragma unroll
  for (int j = 0; j < 16; j++) O[ob + j] = f2bf(acc[j] * inv);
}

// ---------------------------------------------------------------------------
extern "C" void kernel_launch(void* const* d_in, const int* in_sizes, int n_in,
                              void* d_out, int out_size, void* d_ws,
                              size_t ws_size, hipStream_t stream) {
  (void)in_sizes; (void)n_in; (void)out_size; (void)ws_size;
  const float* x = (const float*)d_in[0];
  const void* mask = d_in[2];

  char* ws = (char*)d_ws;
  u16* Wb  = (u16*)(ws);                        // bf16 arena, 23599104 B
  u16* n1h = (u16*)(ws + 23599104);             // 4096x3072 bf16 (h1 / attn partials)
  u16* Qb  = (u16*)(ws + 48764928);             // 4096x768 (later n2)
  u16* Kb2 = (u16*)(ws + 55056384);             // 4096x768
  u16* Vb2 = (u16*)(ws + 61347840);             // 4096x768
  u16* att = (u16*)(ws + 67639296);             // 4096x768 att, later ht (x1536)
  u16* hs  = (u16*)(ws + 80222208);             // 4096x1536 (attn partial spill)
  float* mfl = (float*)(ws + 92805120);         // 768 floats
  float* x1 = (float*)d_out;                    // x / x1 fp32 live in d_out
  float* Pn = (float*)n1h;                      // 1536 partial slots x 4096 f32
  float* Ph = (float*)hs;                       // 192 slots + m/l at +786432 f32
  float* Pt = (float*)Qb;                       // ffn2 ht partial fp32, 12.6MB
  u16* Ps16 = Vb2;                              // ffn2 hs partial bf16, 6.3MB

  u16* Wq = Wb + 0,        *Wk = Wb + 589824,   *Wv = Wb + 1179648;
  u16* Wo = Wb + 1769472,  *w1 = Wb + 2359296,  *w1t = Wb + 4718592;
  u16* w1s = Wb + 5898240, *w2 = Wb + 7077888,  *w2t = Wb + 9437184;
  u16* w2s = Wb + 10616832;
  u16* n1w = Wb + 11796480, *n1b = Wb + 11797248;
  u16* n2w = Wb + 11798016, *n2b = Wb + 11798784;

  Segs sg;
  const int srcidx[14] = {3, 4, 5, 6, 7, 9, 11, 8, 10, 12, 13, 14, 15, 16};
  const int offs[14] = {0, 589824, 1179648, 1769472, 2359296, 4718592,
                        5898240, 7077888, 9437184, 10616832,
                        11796480, 11797248, 11798016, 11798784};
  const int ns[14] = {589824, 589824, 589824, 589824, 2359296, 1179648,
                      1179648, 2359296, 1179648, 1179648, 768, 768, 768, 768};
  const int mms[14] = {0, 0, 0, 0, 0, 1, 2, 0, 0, 0, 0, 0, 0, 0};
  for (int i = 0; i < 14; i++) {
    sg.src[i] = d_in[srcidx[i]];
    sg.off[i] = offs[i];
    sg.n[i] = ns[i];
    sg.mmode[i] = mms[i];
  }

  mask_conv_k<<<1, 256, 0, stream>>>(mask, mfl);
  convert_k<<<dim3(2304, 14), 256, 0, stream>>>(sg, Wb, mfl);

  // n1 = mink_norm(x); also seed d_out with x (residual base for Wo atomics)
  mink_norm_k<<<4096, 256, 0, stream>>>(x, mfl, n1w, n1b, n1h, x1);

  // Q,K,V fused (N=2304), XCD-swizzled
  GArgs qkv;
  qkv.s[0] = {Wq, Qb, 768, 6, 0};
  qkv.s[1] = {Wk, Kb2, 768, 6, 0};
  qkv.s[2] = {Wv, Vb2, 768, 6, 0};
  gemm128_fused<<<dim3(18, 32), 256, 0, stream>>>(n1h, 768, 768, qkv);

  qcorr_k<<<12288, 256, 0, stream>>>(Qb, mfl);

  // flash attention: 80 chunks/bh, partials into Pn/Ph, then merge
  flash_attn_k<<<dim3(80, 24), 256, 0, stream>>>(Qb, Kb2, Vb2, att, Pn, Ph);
  attn_merge_k<<<dim3(24, 24), 256, 0, stream>>>(Pn, Ph, att);

  // x1 = x + att @ Wo^T  (split-K x2 atomic into d_out holding x)
  gemm128_wo_splitk<<<dim3(6, 32, 2), 256, 0, stream>>>(att, Wo, x1);

  // n2 = mink_norm(x1) -> Qb (mask folded into FFN1 weights)
  mink_norm_k<<<4096, 256, 0, stream>>>(x1, mfl, n2w, n2b, Qb, nullptr);

  // FFN1 fused (N=6144): h1 = gelu(n2@w1^T), ht = silu(n2@w1t_m^T),
  // hs = gelu(n2@w1s_m^T), XCD-swizzled
  GArgs ffn1;
  ffn1.s[0] = {w1, n1h, 3072, 24, 2};
  ffn1.s[1] = {w1t, att, 1536, 12, 3};
  ffn1.s[2] = {w1s, hs, 1536, 12, 2};
  gemm128_fused<<<dim3(48, 32), 256, 0, stream>>>(Qb, 768, 768, ffn1);

  // ffn2: 3-way owned-output split (no atomics) + reduce.
  // z=0 RMWs d_out (x1 + 0.5*h1@w2); z=1 -> Pt fp32; z=2 -> Ps16 bf16.
  // Pt/Ps16 live in Qb/Kb2/Vb2, all dead by this point.
  ffn2_split3<<<dim3(6, 32, 3), 256, 0, stream>>>(n1h, att, hs, w2, w2t, w2s,
                                                  (float*)d_out, Pt, Ps16);
  ffn2_reduce<<<3072, 256, 0, stream>>>((float*)d_out, Pt, Ps16);
}

// Round 10
// 434.200 us; speedup vs baseline: 1.0216x; 1.0093x over previous
//
#include <hip/hip_runtime.h>

// LorentzBlock: B=2, L=2048, D=768, H=12, DH=64, DFF=3072
// R20: base = R17 (424.2us best; R18/R19 reverted). Single change: ffn2
// uses 128x64 tiles -> grid (12,32,4)=1536 blocks = 6 blk/CU (vs 3).
// Cycle accounting: ffn2 invariant ~86us across pipe-depth/atomic variants;
// 4300 cy/iter wall with 3 waves/SIMD covering a ~1400cy barrier+load
// chain; MfmaUtil 17% == 3*80/1433 exactly -> latency-bound on waves/SIMD.
// FFN1 (same FLOPs, same loop, 6 blk/CU) is <87us -> occupancy is the lever.
// BN=64: 3 loads/iter (vmcnt(3)), 24KB LDS depth-2, 8 MFMA/wave/iter.

typedef unsigned short u16;
typedef __bf16 bfrag __attribute__((ext_vector_type(8)));
typedef float f32x4 __attribute__((ext_vector_type(4)));

#define MFMA(a, b, c) __builtin_amdgcn_mfma_f32_16x16x32_bf16(a, b, c, 0, 0, 0)
#define NEG_BIG (-30000.0f)
#define ASYNC16(g, l)                                                        \
  __builtin_amdgcn_global_load_lds(                                          \
      (const __attribute__((address_space(1))) unsigned int*)(g),            \
      (__attribute__((address_space(3))) unsigned int*)(l), 16, 0, 0)

__device__ __forceinline__ float bf2f(u16 u) {
  unsigned int v = ((unsigned int)u) << 16;
  float f; __builtin_memcpy(&f, &v, 4); return f;
}
__device__ __forceinline__ u16 f2bf(float f) {
  unsigned int v; __builtin_memcpy(&v, &f, 4);
  v += 0x7fffu + ((v >> 16) & 1u);   // RNE
  return (u16)(v >> 16);
}
__device__ __forceinline__ bfrag ldfrag(const u16* p) {
  bfrag v; __builtin_memcpy(&v, p, 16); return v;
}

// XCD-chunked bijective swizzle of the linear workgroup id. Requires
// nwg % 8 == 0 (all call sites comply); identity fallback otherwise.
__device__ __forceinline__ int xcd_work_id() {
  const int nx = gridDim.x, ny = gridDim.y;
  const int nwg = nx * ny * gridDim.z;
  const int orig = blockIdx.x + nx * (blockIdx.y + ny * blockIdx.z);
  if (nwg & 7) return orig;
  return (orig & 7) * (nwg >> 3) + (orig >> 3);
}

// ---------------------------------------------------------------------------
// Mask canonicalization -> float[768].
// ---------------------------------------------------------------------------
__global__ __launch_bounds__(256) void mask_conv_k(const void* __restrict__ mask,
                                                   float* __restrict__ mfl) {
  __shared__ int msh;
  if (threadIdx.x == 0) msh = 0;
  __syncthreads();
  const unsigned int* w = (const unsigned int*)mask;
  if (threadIdx.x < 192) {
    const unsigned int v = w[threadIdx.x];
    if ((v & 0xFFFFu) == 0x3F80u) atomicOr(&msh, 4);
    else if (v == 0x3F800000u) atomicOr(&msh, 2);
    else if (v >= 2u) atomicOr(&msh, 1);
  }
  __syncthreads();
  const int m = msh;
  const int mode = (m & 4) ? 3 : (m & 2) ? 2 : (m & 1) ? 1 : 0;
  for (int i = threadIdx.x; i < 768; i += 256) {
    int b;
    if (mode == 3) b = ((const u16*)mask)[i] != 0;
    else if (mode == 2) b = ((const float*)mask)[i] != 0.0f;
    else if (mode == 1) b = ((const unsigned char*)mask)[i] != 0;
    else b = ((const int*)mask)[i] != 0;
    mfl[i] = (float)b;
  }
}

// ---------------------------------------------------------------------------
// Convert fp32 weight segments -> bf16 arena. mmode: 0 none, 1 *m[k],
// 2 *(1-m[k]) with k = i % 768 (mask fold for w1_t / w1_s).
// ---------------------------------------------------------------------------
struct Segs {
  const void* src[14];
  int off[14];
  int n[14];
  int mmode[14];
};

__global__ __launch_bounds__(256) void convert_k(Segs segs, u16* __restrict__ dstb,
                                                 const float* __restrict__ mfl) {
  const int seg = blockIdx.y;
  const int n = segs.n[seg];
  const int mm = segs.mmode[seg];
  u16* dst = dstb + segs.off[seg];
  const float* src = (const float*)segs.src[seg];
  for (int i = (blockIdx.x * 256 + threadIdx.x) * 4; i < n; i += gridDim.x * 1024) {
    float4 v;
    __builtin_memcpy(&v, src + i, 16);
    if (mm) {
      const int k = i % 768;
      float m0 = mfl[k], m1 = mfl[k + 1], m2 = mfl[k + 2], m3 = mfl[k + 3];
      if (mm == 2) { m0 = 1.f - m0; m1 = 1.f - m1; m2 = 1.f - m2; m3 = 1.f - m3; }
      v.x *= m0; v.y *= m1; v.z *= m2; v.w *= m3;
    }
    dst[i] = f2bf(v.x); dst[i + 1] = f2bf(v.y);
    dst[i + 2] = f2bf(v.z); dst[i + 3] = f2bf(v.w);
  }
}

// ---------------------------------------------------------------------------
// Minkowski LayerNorm. fp32 input, bf16 output. Optionally copies the raw
// input row to Xcopy (fp32) -- seeds d_out with x for the Wo split-K atomics.
// ---------------------------------------------------------------------------
__global__ __launch_bounds__(256) void mink_norm_k(
    const float* __restrict__ X, const float* __restrict__ mf,
    const u16* __restrict__ w, const u16* __restrict__ bias,
    u16* __restrict__ Y, float* __restrict__ Xcopy) {
  __shared__ float red[8];
  const int row = blockIdx.x, tid = threadIdx.x;
  const int wid = tid >> 6, lane = tid & 63;
  const size_t roff = (size_t)row * 768;

  float xv[3], mv[3];
  int idx[3];
#pragma unroll
  for (int i = 0; i < 3; i++) {
    idx[i] = tid + i * 256;
    xv[i] = X[roff + idx[i]];
    mv[i] = mf[idx[i]];
  }
  if (Xcopy) {
#pragma unroll
    for (int i = 0; i < 3; i++) Xcopy[roff + idx[i]] = xv[i];
  }
  float s = xv[0] + xv[1] + xv[2];
#pragma unroll
  for (int o = 32; o >= 1; o >>= 1) s += __shfl_xor(s, o, 64);
  if (lane == 0) red[wid] = s;
  __syncthreads();
  const float mean = (red[0] + red[1] + red[2] + red[3]) * (1.0f / 768.0f);
  __syncthreads();

  float xc[3], ss = 0.0f, sm = 0.0f;
#pragma unroll
  for (int i = 0; i < 3; i++) {
    xc[i] = xv[i] - mean;
    ss += xc[i] * xc[i];
    sm += xc[i] * xc[i] * mv[i];
  }
#pragma unroll
  for (int o = 32; o >= 1; o >>= 1) {
    ss += __shfl_xor(ss, o, 64);
    sm += __shfl_xor(sm, o, 64);
  }
  if (lane == 0) { red[wid] = ss; red[4 + wid] = sm; }
  __syncthreads();
  const float sumsq = red[0] + red[1] + red[2] + red[3];
  const float summ = red[4] + red[5] + red[6] + red[7];
  const float var = sumsq * (1.0f / 768.0f);
  const float eta = sumsq - 2.0f * summ;
  const float rs = 1.0f / sqrtf(var + 1e-5f);
  const float re = 1.0f / sqrtf(fabsf(eta) + 1e-5f);

#pragma unroll
  for (int i = 0; i < 3; i++) {
    const float xn = xc[i] * 0.5f * (rs + re);
    Y[roff + idx[i]] = f2bf(bf2f(w[idx[i]]) * xn + bf2f(bias[idx[i]]));
  }
}

// ---------------------------------------------------------------------------
// Q Lorentz correction, in place. 4 rows per block (one per wave).
// ---------------------------------------------------------------------------
__global__ __launch_bounds__(256) void qcorr_k(u16* __restrict__ Q,
                                               const float* __restrict__ mf) {
  const int idx = blockIdx.x * 4 + (threadIdx.x >> 6);  // (b*2048+l)*12+h
  const int t = threadIdx.x & 63;
  const int h = idx % 12;
  const int bl = idx / 12;
  const size_t off = (size_t)bl * 768 + h * 64 + t;
  const float q = bf2f(Q[off]);
  const float m = mf[h * 64 + t];
  float q2 = q * q, qm2 = q * q * m;
#pragma unroll
  for (int o = 32; o >= 1; o >>= 1) {
    q2 += __shfl_xor(q2, o, 64);
    qm2 += __shfl_xor(qm2, o, 64);
  }
  const float qn = sqrtf(q2), qtn = sqrtf(qm2);
  const float sf = (qtn > 1e-6f) ? qn / fmaxf(qtn, 1e-8f) : 0.0f;
  Q[off] = f2bf(q * (1.0f - 0.5f * sf * m) * 0.125f);
}

// ---------------------------------------------------------------------------
// 128x128 MFMA GEMM core, counted-vmcnt 2-phase double-buffered (R16/R17).
// ---------------------------------------------------------------------------
__device__ __forceinline__ void gemm128_loop(
    const u16* __restrict__ Ab, const u16* __restrict__ Wb2,
    int K, int lda, int ldb, u16 (*As)[32], u16 (*Bs)[32], f32x4 acc[4][4]) {
  const int tid = threadIdx.x;
  const int wid = tid >> 6, lane = tid & 63;
  const int lr = lane & 15, lq = lane >> 4;
  const int srow = wid * 32 + (lane >> 2);
  const int scol = (lane & 3) * 8;
  const u16* ga0 = Ab + (size_t)srow * lda + scol;
  const u16* ga1 = Ab + (size_t)(srow + 16) * lda + scol;
  const u16* gb0 = Wb2 + (size_t)srow * ldb + scol;
  const u16* gb1 = Wb2 + (size_t)(srow + 16) * ldb + scol;
  const int wr = (wid >> 1) * 64, wc = (wid & 1) * 64;
  const int nt = K >> 5;

#define STAGE16(dbuf, k0)                                                    \
  {                                                                          \
    u16* _a0 = &As[(dbuf) * 128 + wid * 32][0];                              \
    u16* _a1 = &As[(dbuf) * 128 + wid * 32 + 16][0];                         \
    u16* _b0 = &Bs[(dbuf) * 128 + wid * 32][0];                              \
    u16* _b1 = &Bs[(dbuf) * 128 + wid * 32 + 16][0];                         \
    ASYNC16(ga0 + (k0), _a0);                                                \
    ASYNC16(ga1 + (k0), _a1);                                                \
    ASYNC16(gb0 + (k0), _b0);                                                \
    ASYNC16(gb1 + (k0), _b1);                                                \
  }

  STAGE16(0, 0);
  for (int t = 0; t < nt; ++t) {
    const int cur = t & 1;
    if (t + 1 < nt) {
      STAGE16(cur ^ 1, (t + 1) << 5);
      __builtin_amdgcn_sched_barrier(0);
      asm volatile("s_waitcnt vmcnt(4)" ::: "memory");
    } else {
      asm volatile("s_waitcnt vmcnt(0)" ::: "memory");
    }
    __builtin_amdgcn_s_barrier();
    __builtin_amdgcn_sched_barrier(0);
    bfrag af[4], bf4[4];
#pragma unroll
    for (int i = 0; i < 4; i++)
      af[i] = ldfrag(&As[cur * 128 + wr + i * 16 + lr][lq * 8]);
#pragma unroll
    for (int j = 0; j < 4; j++)
      bf4[j] = ldfrag(&Bs[cur * 128 + wc + j * 16 + lr][lq * 8]);
#pragma unroll
    for (int i = 0; i < 4; i++)
#pragma unroll
      for (int j = 0; j < 4; j++)
        acc[i][j] = MFMA(af[i], bf4[j], acc[i][j]);
    asm volatile("s_waitcnt lgkmcnt(0)" ::: "memory");
    __builtin_amdgcn_sched_barrier(0);
    __builtin_amdgcn_s_barrier();
  }
#undef STAGE16
}

// ---------------------------------------------------------------------------
// 128x64 MFMA GEMM core (ffn2): A tile 128x32, B tile 64x32, 3 loads/iter,
// depth-2 counted vmcnt(3). 4 waves in 2x2 over (128,64): each wave 64x32
// output, acc[4][2], 8 MFMA/iter. LDS 24KB -> 6 blocks/CU.
// ---------------------------------------------------------------------------
__device__ __forceinline__ void gemm128x64_loop(
    const u16* __restrict__ Ab, const u16* __restrict__ Wb2,
    int K, int lda, int ldb, u16 (*As)[32], u16 (*Bs)[32], f32x4 acc[4][2]) {
  const int tid = threadIdx.x;
  const int wid = tid >> 6, lane = tid & 63;
  const int lr = lane & 15, lq = lane >> 4;
  const int srowA = wid * 32 + (lane >> 2);
  const int srowB = wid * 16 + (lane >> 2);
  const int scol = (lane & 3) * 8;
  const u16* ga0 = Ab + (size_t)srowA * lda + scol;
  const u16* ga1 = Ab + (size_t)(srowA + 16) * lda + scol;
  const u16* gb0 = Wb2 + (size_t)srowB * ldb + scol;
  const int wr = (wid >> 1) * 64, wc = (wid & 1) * 32;
  const int nt = K >> 5;

#define STAGE64(dbuf, k0)                                                    \
  {                                                                          \
    u16* _a0 = &As[(dbuf) * 128 + wid * 32][0];                              \
    u16* _a1 = &As[(dbuf) * 128 + wid * 32 + 16][0];                         \
    u16* _b0 = &Bs[(dbuf) * 64 + wid * 16][0];                               \
    ASYNC16(ga0 + (k0), _a0);                                                \
    ASYNC16(ga1 + (k0), _a1);                                                \
    ASYNC16(gb0 + (k0), _b0);                                                \
  }

  STAGE64(0, 0);
  for (int t = 0; t < nt; ++t) {
    const int cur = t & 1;
    if (t + 1 < nt) {
      STAGE64(cur ^ 1, (t + 1) << 5);
      __builtin_amdgcn_sched_barrier(0);
      asm volatile("s_waitcnt vmcnt(3)" ::: "memory");
    } else {
      asm volatile("s_waitcnt vmcnt(0)" ::: "memory");
    }
    __builtin_amdgcn_s_barrier();
    __builtin_amdgcn_sched_barrier(0);
    bfrag af[4], bf2[2];
#pragma unroll
    for (int i = 0; i < 4; i++)
      af[i] = ldfrag(&As[cur * 128 + wr + i * 16 + lr][lq * 8]);
#pragma unroll
    for (int j = 0; j < 2; j++)
      bf2[j] = ldfrag(&Bs[cur * 64 + wc + j * 16 + lr][lq * 8]);
#pragma unroll
    for (int i = 0; i < 4; i++)
#pragma unroll
      for (int j = 0; j < 2; j++)
        acc[i][j] = MFMA(af[i], bf2[j], acc[i][j]);
    asm volatile("s_waitcnt lgkmcnt(0)" ::: "memory");
    __builtin_amdgcn_sched_barrier(0);
    __builtin_amdgcn_s_barrier();
  }
#undef STAGE64
}

// ---------------------------------------------------------------------------
// Fused multi-segment GEMM, bf16 out: C_seg = epi(A @ Wseg^T).
// XCD-swizzled work id.
// ---------------------------------------------------------------------------
struct GSeg { const u16* W; u16* C; int ldc; int nblk; int epi; };
struct GArgs { GSeg s[3]; };

__global__ __launch_bounds__(256) void gemm128_fused(
    const u16* __restrict__ A, int lda, int K, GArgs args) {
  __shared__ __align__(16) u16 As[256][32];
  __shared__ __align__(16) u16 Bs[256][32];
  const int w = xcd_work_id();
  int cb = w % gridDim.x, seg = 0;
  const int by = w / gridDim.x;
  while (cb >= args.s[seg].nblk) { cb -= args.s[seg].nblk; seg++; }
  const GSeg g = args.s[seg];
  const int rowb = by * 128, colb = cb * 128;
  f32x4 acc[4][4] = {};
  gemm128_loop(A + (size_t)rowb * lda, g.W + (size_t)colb * K, K, lda, K,
               As, Bs, acc);

  const int lane = threadIdx.x & 63, wid = threadIdx.x >> 6;
  const int lr = lane & 15, lq = lane >> 4;
  const int wr = (wid >> 1) * 64, wc = (wid & 1) * 64;
#pragma unroll
  for (int i = 0; i < 4; i++)
#pragma unroll
    for (int j = 0; j < 4; j++)
#pragma unroll
      for (int r = 0; r < 4; r++) {
        const int row = rowb + wr + i * 16 + lq * 4 + r;
        const int col = colb + wc + j * 16 + lr;
        float v = acc[i][j][r];
        if (g.epi == 2) v = 0.5f * v * (1.0f + erff(v * 0.70710678118654752f));
        else if (g.epi == 3) v = v / (1.0f + __expf(-v));
        g.C[(size_t)row * g.ldc + col] = f2bf(v);
      }
}

// ---------------------------------------------------------------------------
// Wo projection split-K x2: Out += att @ Wo^T partial. Out (d_out) holds x.
// Depth-2 pipeline, XCD-swizzled.
// ---------------------------------------------------------------------------
__global__ __launch_bounds__(256) void gemm128_wo_splitk(
    const u16* __restrict__ A, const u16* __restrict__ W,
    float* __restrict__ Out) {
  __shared__ __align__(16) u16 As[256][32];
  __shared__ __align__(16) u16 Bs[256][32];
  const int w = xcd_work_id();
  const int bx = w % gridDim.x;
  const int by = (w / gridDim.x) % gridDim.y;
  const int z = w / (gridDim.x * gridDim.y);
  const int rowb = by * 128, colb = bx * 128;
  f32x4 acc[4][4] = {};
  gemm128_loop(A + (size_t)rowb * 768 + z * 384,
               W + (size_t)colb * 768 + z * 384, 384, 768, 768, As, Bs, acc);

  const int lane = threadIdx.x & 63, wid = threadIdx.x >> 6;
  const int lr = lane & 15, lq = lane >> 4;
  const int wr = (wid >> 1) * 64, wc = (wid & 1) * 64;
#pragma unroll
  for (int i = 0; i < 4; i++)
#pragma unroll
    for (int j = 0; j < 4; j++)
#pragma unroll
      for (int r = 0; r < 4; r++) {
        const int row = rowb + wr + i * 16 + lq * 4 + r;
        const int col = colb + wc + j * 16 + lr;
        atomicAdd(&Out[(size_t)row * 768 + col], acc[i][j][r]);
      }
}

// ---------------------------------------------------------------------------
// FFN2 split-K x4 with 128x64 tiles: Out += 0.5 * partial (Out holds x1).
// grid (12,32,4) = 1536 blocks = 6/CU. z selects the K chunk:
//   z=0: h1[:,0:1536)    @ w2[:,0:1536)^T
//   z=1: h1[:,1536:3072) @ w2[:,1536:3072)^T
//   z=2: ht @ w2t^T   (K=1536)
//   z=3: hs @ w2s^T   (K=1536)
// XCD-swizzled (x fastest -> 12 col-blocks of one A panel colocate).
// ---------------------------------------------------------------------------
__global__ __launch_bounds__(256) void ffn2_splitk64(
    const u16* __restrict__ H1, const u16* __restrict__ Ht,
    const u16* __restrict__ Hs, const u16* __restrict__ W2,
    const u16* __restrict__ W2t, const u16* __restrict__ W2s,
    float* __restrict__ Out) {
  __shared__ __align__(16) u16 As[256][32];
  __shared__ __align__(16) u16 Bs[128][32];
  const int w = xcd_work_id();
  const int bx = w % gridDim.x;
  const int by = (w / gridDim.x) % gridDim.y;
  const int z = w / (gridDim.x * gridDim.y);
  const int rowb = by * 128, colb = bx * 64;
  f32x4 acc[4][2] = {};
  if (z == 0)
    gemm128x64_loop(H1 + (size_t)rowb * 3072, W2 + (size_t)colb * 3072,
                    1536, 3072, 3072, As, Bs, acc);
  else if (z == 1)
    gemm128x64_loop(H1 + (size_t)rowb * 3072 + 1536,
                    W2 + (size_t)colb * 3072 + 1536,
                    1536, 3072, 3072, As, Bs, acc);
  else if (z == 2)
    gemm128x64_loop(Ht + (size_t)rowb * 1536, W2t + (size_t)colb * 1536,
                    1536, 1536, 1536, As, Bs, acc);
  else
    gemm128x64_loop(Hs + (size_t)rowb * 1536, W2s + (size_t)colb * 1536,
                    1536, 1536, 1536, As, Bs, acc);

  const int lane = threadIdx.x & 63, wid = threadIdx.x >> 6;
  const int lr = lane & 15, lq = lane >> 4;
  const int wr = (wid >> 1) * 64, wc = (wid & 1) * 32;
#pragma unroll
  for (int i = 0; i < 4; i++)
#pragma unroll
    for (int j = 0; j < 2; j++)
#pragma unroll
      for (int r = 0; r < 4; r++) {
        const int row = rowb + wr + i * 16 + lq * 4 + r;
        const int col = colb + wc + j * 16 + lr;
        atomicAdd(&Out[(size_t)row * 768 + col], 0.5f * acc[i][j][r]);
      }
}

// ---------------------------------------------------------------------------
// Flash attention producer, causal, KV-split (R13, unchanged). QBLK=64,
// 4 waves. Per bh: 80 chunks; qt<8 writes final; else (O,m,l) partial.
// ---------------------------------------------------------------------------
__global__ __launch_bounds__(256) void flash_attn_k(
    const u16* __restrict__ Qc, const u16* __restrict__ Kb,
    const u16* __restrict__ Vb, u16* __restrict__ O,
    float* __restrict__ Pn, float* __restrict__ Ph) {
  __shared__ __align__(16) u16 Ks[64][40];
  __shared__ __align__(16) u16 Vt[64][72];
  __shared__ __align__(16) u16 Ps[4][16][72];
  const int tid = threadIdx.x, wid = tid >> 6, lane = tid & 63;
  const int lr = lane & 15, lq = lane >> 4;

  // decode blockIdx.x -> (qt, c); qt descending so long chunks launch first
  int bx = blockIdx.x, qt = 0, c = 0;
  for (int q = 31; q >= 0; --q) {
    const int nc = (q < 8) ? 1 : (q / 8 + 1);
    if (bx < nc) { qt = q; c = bx; break; }
    bx -= nc;
  }
  const int nt = qt + 1;
  const int t0 = c * 8;
  const int t1 = (t0 + 8 < nt) ? t0 + 8 : nt;

  const int qb = qt * 64;
  const int bh = blockIdx.y;
  const int b = bh / 12, h = bh % 12;
  const int q0 = qb + wid * 16;
  const size_t base = (size_t)b * 2048 * 768 + h * 64;

  bfrag aq[2];
  aq[0] = ldfrag(Qc + base + (size_t)(q0 + lr) * 768 + lq * 8);
  aq[1] = ldfrag(Qc + base + (size_t)(q0 + lr) * 768 + 32 + lq * 8);

  f32x4 o[4] = {};
  float mrow[4] = {NEG_BIG, NEG_BIG, NEG_BIG, NEG_BIG};
  float lrow[4] = {0.0f, 0.0f, 0.0f, 0.0f};

  const int krow = tid >> 3;        // 0..31
  const int kcol = (tid & 7) * 8;
  const int vkey = tid & 31;
  const int vdg = tid >> 5;         // 0..7

  const u16* kp = Kb + base + (size_t)(t0 * 64 + krow) * 768 + kcol;
  const u16* vp = Vb + base + (size_t)(t0 * 64 + vkey) * 768 + vdg * 8;

  uint4 kv0, kv1, vv0, vv1;
  __builtin_memcpy(&kv0, kp, 16);
  __builtin_memcpy(&kv1, kp + (size_t)32 * 768, 16);
  __builtin_memcpy(&vv0, vp, 16);
  __builtin_memcpy(&vv1, vp + (size_t)32 * 768, 16);

  for (int kt = t0; kt < t1; kt++) {
    __syncthreads();
    __builtin_memcpy(&Ks[krow][kcol], &kv0, 16);
    __builtin_memcpy(&Ks[krow + 32][kcol], &kv1, 16);
    {
      union { uint4 u; u16 s[8]; } a, b2;
      a.u = vv0; b2.u = vv1;
#pragma unroll
      for (int j = 0; j < 8; j++) {
        Vt[vdg * 8 + j][vkey] = a.s[j];
        Vt[vdg * 8 + j][vkey + 32] = b2.s[j];
      }
    }
    __syncthreads();
    if (kt + 1 < t1) {
      const size_t koff = (size_t)(kt + 1 - t0) * 64 * 768;
      __builtin_memcpy(&kv0, kp + koff, 16);
      __builtin_memcpy(&kv1, kp + koff + (size_t)32 * 768, 16);
      __builtin_memcpy(&vv0, vp + koff, 16);
      __builtin_memcpy(&vv1, vp + koff + (size_t)32 * 768, 16);
    }

    const int kbk = kt * 64;
    {
      f32x4 s4[4] = {};
#pragma unroll
      for (int kg = 0; kg < 2; kg++) {
#pragma unroll
        for (int cc = 0; cc < 4; cc++) {
          bfrag bk = ldfrag(&Ks[cc * 16 + lr][kg * 32 + lq * 8]);
          s4[cc] = MFMA(aq[kg], bk, s4[cc]);
        }
      }
#pragma unroll
      for (int r = 0; r < 4; r++) {
        const int q = q0 + lq * 4 + r;
        float v[4];
        float mx = NEG_BIG;
#pragma unroll
        for (int cc = 0; cc < 4; cc++) {
          v[cc] = (kbk + cc * 16 + lr > q) ? NEG_BIG : s4[cc][r];
          mx = fmaxf(mx, v[cc]);
        }
#pragma unroll
        for (int off = 8; off >= 1; off >>= 1)
          mx = fmaxf(mx, __shfl_xor(mx, off, 16));
        const float mn = fmaxf(mrow[r], mx);
        const float alpha = __expf(mrow[r] - mn);
        float sm = 0.0f;
        float p[4];
#pragma unroll
        for (int cc = 0; cc < 4; cc++) {
          p[cc] = __expf(v[cc] - mn);
          sm += p[cc];
        }
#pragma unroll
        for (int off = 8; off >= 1; off >>= 1) sm += __shfl_xor(sm, off, 16);
        lrow[r] = lrow[r] * alpha + sm;
        mrow[r] = mn;
#pragma unroll
        for (int dt = 0; dt < 4; dt++) o[dt][r] *= alpha;
#pragma unroll
        for (int cc = 0; cc < 4; cc++)
          Ps[wid][lq * 4 + r][cc * 16 + lr] = f2bf(p[cc]);
      }
      __threadfence_block();
      bfrag pf0 = ldfrag(&Ps[wid][lr][lq * 8]);
      bfrag pf1 = ldfrag(&Ps[wid][lr][32 + lq * 8]);
#pragma unroll
      for (int dt = 0; dt < 4; dt++) {
        bfrag v0 = ldfrag(&Vt[dt * 16 + lr][lq * 8]);
        bfrag v1 = ldfrag(&Vt[dt * 16 + lr][32 + lq * 8]);
        o[dt] = MFMA(pf0, v0, o[dt]);
        o[dt] = MFMA(pf1, v1, o[dt]);
      }
    }
  }

  if (qt < 8) {
    // final: normalize and write bf16
#pragma unroll
    for (int r = 0; r < 4; r++) {
      const float inv = 1.0f / fmaxf(lrow[r], 1e-30f);
      const int q = q0 + lq * 4 + r;
#pragma unroll
      for (int dt = 0; dt < 4; dt++)
        O[base + (size_t)q * 768 + dt * 16 + lr] = f2bf(o[dt][r] * inv);
    }
  } else {
    // partial: slot s = bh*72 + off(qt) + c
    int off = 0;
    for (int j = 8; j < qt; ++j) off += j / 8 + 1;
    const int s = bh * 72 + off + c;
    float* Op = (s < 1536) ? Pn + (size_t)s * 4096
                           : Ph + (size_t)(s - 1536) * 4096;
    float* lmp = Ph + 786432 + (size_t)s * 128;
#pragma unroll
    for (int r = 0; r < 4; r++) {
      const int row = wid * 16 + lq * 4 + r;
#pragma unroll
      for (int dt = 0; dt < 4; dt++)
        Op[(size_t)row * 64 + dt * 16 + lr] = o[dt][r];
      if (lr == 0) { lmp[row] = mrow[r]; lmp[64 + row] = lrow[r]; }
    }
  }
}

// ---------------------------------------------------------------------------
// Merge partials for qt in [8,32): O = sum_c exp(m_c-m_g)*O_c / l_g.
// grid (24, 24): x = qt-8, y = bh.
// ---------------------------------------------------------------------------
__global__ __launch_bounds__(256) void attn_merge_k(
    const float* __restrict__ Pn, const float* __restrict__ Ph,
    u16* __restrict__ O) {
  const int qt = 8 + blockIdx.x;
  const int bh = blockIdx.y;
  const int b = bh / 12, h = bh % 12;
  const int nc = qt / 8 + 1;
  int off = 0;
  for (int j = 8; j < qt; ++j) off += j / 8 + 1;
  const int s0 = bh * 72 + off;
  const int row = threadIdx.x >> 2;
  const int c0 = (threadIdx.x & 3) * 16;
  const float* lmb = Ph + 786432;

  float mg = NEG_BIG;
  for (int cc = 0; cc < nc; ++cc)
    mg = fmaxf(mg, lmb[(size_t)(s0 + cc) * 128 + row]);

  float acc[16];
#pragma unroll
  for (int j = 0; j < 16; j++) acc[j] = 0.0f;
  float lg = 0.0f;
  for (int cc = 0; cc < nc; ++cc) {
    const int s = s0 + cc;
    const float mcv = lmb[(size_t)s * 128 + row];
    const float coef = __expf(mcv - mg);
    lg += coef * lmb[(size_t)s * 128 + 64 + row];
    const float* Op = (s < 1536) ? Pn + (size_t)s * 4096
                                 : Ph + (size_t)(s - 1536) * 4096;
    const float* rp = Op + (size_t)row * 64 + c0;
#pragma unroll
    for (int g = 0; g < 4; g++) {
      float4 v;
      __builtin_memcpy(&v, rp + g * 4, 16);
      acc[g * 4 + 0] += coef * v.x;
      acc[g * 4 + 1] += coef * v.y;
      acc[g * 4 + 2] += coef * v.z;
      acc[g * 4 + 3] += coef * v.w;
    }
  }
  const float inv = 1.0f / fmaxf(lg, 1e-30f);
  const int q = qt * 64 + row;
  const size_t ob = (size_t)b * 2048 * 768 + h * 64 + (size_t)q * 768 + c0;
#pragma unroll
  for (int j = 0; j < 16; j++) O[ob + j] = f2bf(acc[j] * inv);
}

// ---------------------------------------------------------------------------
extern "C" void kernel_launch(void* const* d_in, const int* in_sizes, int n_in,
                              void* d_out, int out_size, void* d_ws,
                              size_t ws_size, hipStream_t stream) {
  (void)in_sizes; (void)n_in; (void)out_size; (void)ws_size;
  const float* x = (const float*)d_in[0];
  const void* mask = d_in[2];

  char* ws = (char*)d_ws;
  u16* Wb  = (u16*)(ws);                        // bf16 arena, 23599104 B
  u16* n1h = (u16*)(ws + 23599104);             // 4096x3072 bf16 (h1 / attn partials)
  u16* Qb  = (u16*)(ws + 48764928);             // 4096x768 (later n2)
  u16* Kb2 = (u16*)(ws + 55056384);             // 4096x768
  u16* Vb2 = (u16*)(ws + 61347840);             // 4096x768
  u16* att = (u16*)(ws + 67639296);             // 4096x768 att, later ht (x1536)
  u16* hs  = (u16*)(ws + 80222208);             // 4096x1536 (attn partial spill)
  float* mfl = (float*)(ws + 92805120);         // 768 floats
  float* x1 = (float*)d_out;                    // x / x1 fp32 live in d_out
  float* Pn = (float*)n1h;                      // 1536 partial slots x 4096 f32
  float* Ph = (float*)hs;                       // 192 slots + m/l at +786432 f32

  u16* Wq = Wb + 0,        *Wk = Wb + 589824,   *Wv = Wb + 1179648;
  u16* Wo = Wb + 1769472,  *w1 = Wb + 2359296,  *w1t = Wb + 4718592;
  u16* w1s = Wb + 5898240, *w2 = Wb + 7077888,  *w2t = Wb + 9437184;
  u16* w2s = Wb + 10616832;
  u16* n1w = Wb + 11796480, *n1b = Wb + 11797248;
  u16* n2w = Wb + 11798016, *n2b = Wb + 11798784;

  Segs sg;
  const int srcidx[14] = {3, 4, 5, 6, 7, 9, 11, 8, 10, 12, 13, 14, 15, 16};
  const int offs[14] = {0, 589824, 1179648, 1769472, 2359296, 4718592,
                        5898240, 7077888, 9437184, 10616832,
                        11796480, 11797248, 11798016, 11798784};
  const int ns[14] = {589824, 589824, 589824, 589824, 2359296, 1179648,
                      1179648, 2359296, 1179648, 1179648, 768, 768, 768, 768};
  const int mms[14] = {0, 0, 0, 0, 0, 1, 2, 0, 0, 0, 0, 0, 0, 0};
  for (int i = 0; i < 14; i++) {
    sg.src[i] = d_in[srcidx[i]];
    sg.off[i] = offs[i];
    sg.n[i] = ns[i];
    sg.mmode[i] = mms[i];
  }

  mask_conv_k<<<1, 256, 0, stream>>>(mask, mfl);
  convert_k<<<dim3(2304, 14), 256, 0, stream>>>(sg, Wb, mfl);

  // n1 = mink_norm(x); also seed d_out with x (residual base for Wo atomics)
  mink_norm_k<<<4096, 256, 0, stream>>>(x, mfl, n1w, n1b, n1h, x1);

  // Q,K,V fused (N=2304), XCD-swizzled
  GArgs qkv;
  qkv.s[0] = {Wq, Qb, 768, 6, 0};
  qkv.s[1] = {Wk, Kb2, 768, 6, 0};
  qkv.s[2] = {Wv, Vb2, 768, 6, 0};
  gemm128_fused<<<dim3(18, 32), 256, 0, stream>>>(n1h, 768, 768, qkv);

  qcorr_k<<<12288, 256, 0, stream>>>(Qb, mfl);

  // flash attention: 80 chunks/bh, partials into Pn/Ph, then merge
  flash_attn_k<<<dim3(80, 24), 256, 0, stream>>>(Qb, Kb2, Vb2, att, Pn, Ph);
  attn_merge_k<<<dim3(24, 24), 256, 0, stream>>>(Pn, Ph, att);

  // x1 = x + att @ Wo^T  (split-K x2 atomic into d_out holding x)
  gemm128_wo_splitk<<<dim3(6, 32, 2), 256, 0, stream>>>(att, Wo, x1);

  // n2 = mink_norm(x1) -> Qb (mask folded into FFN1 weights)
  mink_norm_k<<<4096, 256, 0, stream>>>(x1, mfl, n2w, n2b, Qb, nullptr);

  // FFN1 fused (N=6144): h1 = gelu(n2@w1^T), ht = silu(n2@w1t_m^T),
  // hs = gelu(n2@w1s_m^T), XCD-swizzled
  GArgs ffn1;
  ffn1.s[0] = {w1, n1h, 3072, 24, 2};
  ffn1.s[1] = {w1t, att, 1536, 12, 3};
  ffn1.s[2] = {w1s, hs, 1536, 12, 2};
  gemm128_fused<<<dim3(48, 32), 256, 0, stream>>>(Qb, 768, 768, ffn1);

  // out = x1 + 0.5*(h1@w2^T + ht@w2_t^T + hs@w2_s^T), 128x64 tiles,
  // split-K x4 atomic, 1536 blocks = 6/CU
  ffn2_splitk64<<<dim3(12, 32, 4), 256, 0, stream>>>(n1h, att, hs, w2, w2t,
                                                     w2s, (float*)d_out);
}

// Round 11
// 421.452 us; speedup vs baseline: 1.0525x; 1.0302x over previous
//
#include <hip/hip_runtime.h>

// LorentzBlock: B=2, L=2048, D=768, H=12, DH=64, DFF=3072
// R21: (a) ffn2 reverted to R17 128x2 x4 split (R20's 128x64 regressed:
// occupancy 27->50% with MfmaUtil unchanged -> per-iter wall is not
// wave-coverable; ffn2 ~86us is this structure's floor, stop grinding);
// (b) qcorr fused into QKV epilogue (wave owns one head-aligned 64-col
// block; 16-lane shfl_xor reduce) -- kills a 12288-block launch + 25MB RT;
// (c) Wo 128x64 tiles -> (12,32,2)=768 blocks=3/CU (was 1.5/CU, idle CUs).
// Keeps R17 depth-2 counted-vmcnt loop + XCD swizzle + R13 flash-decode.

typedef unsigned short u16;
typedef __bf16 bfrag __attribute__((ext_vector_type(8)));
typedef float f32x4 __attribute__((ext_vector_type(4)));

#define MFMA(a, b, c) __builtin_amdgcn_mfma_f32_16x16x32_bf16(a, b, c, 0, 0, 0)
#define NEG_BIG (-30000.0f)
#define ASYNC16(g, l)                                                        \
  __builtin_amdgcn_global_load_lds(                                          \
      (const __attribute__((address_space(1))) unsigned int*)(g),            \
      (__attribute__((address_space(3))) unsigned int*)(l), 16, 0, 0)

__device__ __forceinline__ float bf2f(u16 u) {
  unsigned int v = ((unsigned int)u) << 16;
  float f; __builtin_memcpy(&f, &v, 4); return f;
}
__device__ __forceinline__ u16 f2bf(float f) {
  unsigned int v; __builtin_memcpy(&v, &f, 4);
  v += 0x7fffu + ((v >> 16) & 1u);   // RNE
  return (u16)(v >> 16);
}
__device__ __forceinline__ bfrag ldfrag(const u16* p) {
  bfrag v; __builtin_memcpy(&v, p, 16); return v;
}

// XCD-chunked bijective swizzle of the linear workgroup id. Requires
// nwg % 8 == 0 (all call sites comply); identity fallback otherwise.
__device__ __forceinline__ int xcd_work_id() {
  const int nx = gridDim.x, ny = gridDim.y;
  const int nwg = nx * ny * gridDim.z;
  const int orig = blockIdx.x + nx * (blockIdx.y + ny * blockIdx.z);
  if (nwg & 7) return orig;
  return (orig & 7) * (nwg >> 3) + (orig >> 3);
}

// ---------------------------------------------------------------------------
// Mask canonicalization -> float[768].
// ---------------------------------------------------------------------------
__global__ __launch_bounds__(256) void mask_conv_k(const void* __restrict__ mask,
                                                   float* __restrict__ mfl) {
  __shared__ int msh;
  if (threadIdx.x == 0) msh = 0;
  __syncthreads();
  const unsigned int* w = (const unsigned int*)mask;
  if (threadIdx.x < 192) {
    const unsigned int v = w[threadIdx.x];
    if ((v & 0xFFFFu) == 0x3F80u) atomicOr(&msh, 4);
    else if (v == 0x3F800000u) atomicOr(&msh, 2);
    else if (v >= 2u) atomicOr(&msh, 1);
  }
  __syncthreads();
  const int m = msh;
  const int mode = (m & 4) ? 3 : (m & 2) ? 2 : (m & 1) ? 1 : 0;
  for (int i = threadIdx.x; i < 768; i += 256) {
    int b;
    if (mode == 3) b = ((const u16*)mask)[i] != 0;
    else if (mode == 2) b = ((const float*)mask)[i] != 0.0f;
    else if (mode == 1) b = ((const unsigned char*)mask)[i] != 0;
    else b = ((const int*)mask)[i] != 0;
    mfl[i] = (float)b;
  }
}

// ---------------------------------------------------------------------------
// Convert fp32 weight segments -> bf16 arena. mmode: 0 none, 1 *m[k],
// 2 *(1-m[k]) with k = i % 768 (mask fold for w1_t / w1_s).
// ---------------------------------------------------------------------------
struct Segs {
  const void* src[14];
  int off[14];
  int n[14];
  int mmode[14];
};

__global__ __launch_bounds__(256) void convert_k(Segs segs, u16* __restrict__ dstb,
                                                 const float* __restrict__ mfl) {
  const int seg = blockIdx.y;
  const int n = segs.n[seg];
  const int mm = segs.mmode[seg];
  u16* dst = dstb + segs.off[seg];
  const float* src = (const float*)segs.src[seg];
  for (int i = (blockIdx.x * 256 + threadIdx.x) * 4; i < n; i += gridDim.x * 1024) {
    float4 v;
    __builtin_memcpy(&v, src + i, 16);
    if (mm) {
      const int k = i % 768;
      float m0 = mfl[k], m1 = mfl[k + 1], m2 = mfl[k + 2], m3 = mfl[k + 3];
      if (mm == 2) { m0 = 1.f - m0; m1 = 1.f - m1; m2 = 1.f - m2; m3 = 1.f - m3; }
      v.x *= m0; v.y *= m1; v.z *= m2; v.w *= m3;
    }
    dst[i] = f2bf(v.x); dst[i + 1] = f2bf(v.y);
    dst[i + 2] = f2bf(v.z); dst[i + 3] = f2bf(v.w);
  }
}

// ---------------------------------------------------------------------------
// Minkowski LayerNorm. fp32 input, bf16 output. Optionally copies the raw
// input row to Xcopy (fp32) -- seeds d_out with x for the Wo split-K atomics.
// ---------------------------------------------------------------------------
__global__ __launch_bounds__(256) void mink_norm_k(
    const float* __restrict__ X, const float* __restrict__ mf,
    const u16* __restrict__ w, const u16* __restrict__ bias,
    u16* __restrict__ Y, float* __restrict__ Xcopy) {
  __shared__ float red[8];
  const int row = blockIdx.x, tid = threadIdx.x;
  const int wid = tid >> 6, lane = tid & 63;
  const size_t roff = (size_t)row * 768;

  float xv[3], mv[3];
  int idx[3];
#pragma unroll
  for (int i = 0; i < 3; i++) {
    idx[i] = tid + i * 256;
    xv[i] = X[roff + idx[i]];
    mv[i] = mf[idx[i]];
  }
  if (Xcopy) {
#pragma unroll
    for (int i = 0; i < 3; i++) Xcopy[roff + idx[i]] = xv[i];
  }
  float s = xv[0] + xv[1] + xv[2];
#pragma unroll
  for (int o = 32; o >= 1; o >>= 1) s += __shfl_xor(s, o, 64);
  if (lane == 0) red[wid] = s;
  __syncthreads();
  const float mean = (red[0] + red[1] + red[2] + red[3]) * (1.0f / 768.0f);
  __syncthreads();

  float xc[3], ss = 0.0f, sm = 0.0f;
#pragma unroll
  for (int i = 0; i < 3; i++) {
    xc[i] = xv[i] - mean;
    ss += xc[i] * xc[i];
    sm += xc[i] * xc[i] * mv[i];
  }
#pragma unroll
  for (int o = 32; o >= 1; o >>= 1) {
    ss += __shfl_xor(ss, o, 64);
    sm += __shfl_xor(sm, o, 64);
  }
  if (lane == 0) { red[wid] = ss; red[4 + wid] = sm; }
  __syncthreads();
  const float sumsq = red[0] + red[1] + red[2] + red[3];
  const float summ = red[4] + red[5] + red[6] + red[7];
  const float var = sumsq * (1.0f / 768.0f);
  const float eta = sumsq - 2.0f * summ;
  const float rs = 1.0f / sqrtf(var + 1e-5f);
  const float re = 1.0f / sqrtf(fabsf(eta) + 1e-5f);

#pragma unroll
  for (int i = 0; i < 3; i++) {
    const float xn = xc[i] * 0.5f * (rs + re);
    Y[roff + idx[i]] = f2bf(bf2f(w[idx[i]]) * xn + bf2f(bias[idx[i]]));
  }
}

// ---------------------------------------------------------------------------
// 128x128 MFMA GEMM core, counted-vmcnt 2-phase double-buffered (R16/R17).
// ---------------------------------------------------------------------------
__device__ __forceinline__ void gemm128_loop(
    const u16* __restrict__ Ab, const u16* __restrict__ Wb2,
    int K, int lda, int ldb, u16 (*As)[32], u16 (*Bs)[32], f32x4 acc[4][4]) {
  const int tid = threadIdx.x;
  const int wid = tid >> 6, lane = tid & 63;
  const int lr = lane & 15, lq = lane >> 4;
  const int srow = wid * 32 + (lane >> 2);
  const int scol = (lane & 3) * 8;
  const u16* ga0 = Ab + (size_t)srow * lda + scol;
  const u16* ga1 = Ab + (size_t)(srow + 16) * lda + scol;
  const u16* gb0 = Wb2 + (size_t)srow * ldb + scol;
  const u16* gb1 = Wb2 + (size_t)(srow + 16) * ldb + scol;
  const int wr = (wid >> 1) * 64, wc = (wid & 1) * 64;
  const int nt = K >> 5;

#define STAGE16(dbuf, k0)                                                    \
  {                                                                          \
    u16* _a0 = &As[(dbuf) * 128 + wid * 32][0];                              \
    u16* _a1 = &As[(dbuf) * 128 + wid * 32 + 16][0];                         \
    u16* _b0 = &Bs[(dbuf) * 128 + wid * 32][0];                              \
    u16* _b1 = &Bs[(dbuf) * 128 + wid * 32 + 16][0];                         \
    ASYNC16(ga0 + (k0), _a0);                                                \
    ASYNC16(ga1 + (k0), _a1);                                                \
    ASYNC16(gb0 + (k0), _b0);                                                \
    ASYNC16(gb1 + (k0), _b1);                                                \
  }

  STAGE16(0, 0);
  for (int t = 0; t < nt; ++t) {
    const int cur = t & 1;
    if (t + 1 < nt) {
      STAGE16(cur ^ 1, (t + 1) << 5);
      __builtin_amdgcn_sched_barrier(0);
      asm volatile("s_waitcnt vmcnt(4)" ::: "memory");
    } else {
      asm volatile("s_waitcnt vmcnt(0)" ::: "memory");
    }
    __builtin_amdgcn_s_barrier();
    __builtin_amdgcn_sched_barrier(0);
    bfrag af[4], bf4[4];
#pragma unroll
    for (int i = 0; i < 4; i++)
      af[i] = ldfrag(&As[cur * 128 + wr + i * 16 + lr][lq * 8]);
#pragma unroll
    for (int j = 0; j < 4; j++)
      bf4[j] = ldfrag(&Bs[cur * 128 + wc + j * 16 + lr][lq * 8]);
#pragma unroll
    for (int i = 0; i < 4; i++)
#pragma unroll
      for (int j = 0; j < 4; j++)
        acc[i][j] = MFMA(af[i], bf4[j], acc[i][j]);
    asm volatile("s_waitcnt lgkmcnt(0)" ::: "memory");
    __builtin_amdgcn_sched_barrier(0);
    __builtin_amdgcn_s_barrier();
  }
#undef STAGE16
}

// ---------------------------------------------------------------------------
// 128x64 MFMA GEMM core (Wo): A tile 128x32, B tile 64x32, 3 loads/iter,
// depth-2 counted vmcnt(3). 4 waves in 2x2 over (128,64): each wave 64x32
// output, acc[4][2]. LDS 24KB. (Verified in R20.)
// ---------------------------------------------------------------------------
__device__ __forceinline__ void gemm128x64_loop(
    const u16* __restrict__ Ab, const u16* __restrict__ Wb2,
    int K, int lda, int ldb, u16 (*As)[32], u16 (*Bs)[32], f32x4 acc[4][2]) {
  const int tid = threadIdx.x;
  const int wid = tid >> 6, lane = tid & 63;
  const int lr = lane & 15, lq = lane >> 4;
  const int srowA = wid * 32 + (lane >> 2);
  const int srowB = wid * 16 + (lane >> 2);
  const int scol = (lane & 3) * 8;
  const u16* ga0 = Ab + (size_t)srowA * lda + scol;
  const u16* ga1 = Ab + (size_t)(srowA + 16) * lda + scol;
  const u16* gb0 = Wb2 + (size_t)srowB * ldb + scol;
  const int wr = (wid >> 1) * 64, wc = (wid & 1) * 32;
  const int nt = K >> 5;

#define STAGE64(dbuf, k0)                                                    \
  {                                                                          \
    u16* _a0 = &As[(dbuf) * 128 + wid * 32][0];                              \
    u16* _a1 = &As[(dbuf) * 128 + wid * 32 + 16][0];                         \
    u16* _b0 = &Bs[(dbuf) * 64 + wid * 16][0];                               \
    ASYNC16(ga0 + (k0), _a0);                                                \
    ASYNC16(ga1 + (k0), _a1);                                                \
    ASYNC16(gb0 + (k0), _b0);                                                \
  }

  STAGE64(0, 0);
  for (int t = 0; t < nt; ++t) {
    const int cur = t & 1;
    if (t + 1 < nt) {
      STAGE64(cur ^ 1, (t + 1) << 5);
      __builtin_amdgcn_sched_barrier(0);
      asm volatile("s_waitcnt vmcnt(3)" ::: "memory");
    } else {
      asm volatile("s_waitcnt vmcnt(0)" ::: "memory");
    }
    __builtin_amdgcn_s_barrier();
    __builtin_amdgcn_sched_barrier(0);
    bfrag af[4], bf2[2];
#pragma unroll
    for (int i = 0; i < 4; i++)
      af[i] = ldfrag(&As[cur * 128 + wr + i * 16 + lr][lq * 8]);
#pragma unroll
    for (int j = 0; j < 2; j++)
      bf2[j] = ldfrag(&Bs[cur * 64 + wc + j * 16 + lr][lq * 8]);
#pragma unroll
    for (int i = 0; i < 4; i++)
#pragma unroll
      for (int j = 0; j < 2; j++)
        acc[i][j] = MFMA(af[i], bf2[j], acc[i][j]);
    asm volatile("s_waitcnt lgkmcnt(0)" ::: "memory");
    __builtin_amdgcn_sched_barrier(0);
    __builtin_amdgcn_s_barrier();
  }
#undef STAGE64
}

// ---------------------------------------------------------------------------
// Fused multi-segment GEMM, bf16 out: C_seg = epi(A @ Wseg^T).
// epi: 0 none, 1 Lorentz-Q correction (fused qcorr), 2 gelu, 3 silu.
// epi==1: each wave's 64 output cols are one head-aligned block; per row,
// q2/qm2 reduce over j(4 regs) x lr(16 lanes) via shfl_xor 8..1 (stays in
// lq group), then q *= (1 - 0.5*sf*m) * 0.125 (flash pre-scale folded).
// ---------------------------------------------------------------------------
struct GSeg { const u16* W; u16* C; int ldc; int nblk; int epi; };
struct GArgs { GSeg s[3]; };

__global__ __launch_bounds__(256) void gemm128_fused(
    const u16* __restrict__ A, int lda, int K, GArgs args,
    const float* __restrict__ mfl) {
  __shared__ __align__(16) u16 As[256][32];
  __shared__ __align__(16) u16 Bs[256][32];
  const int w = xcd_work_id();
  int cb = w % gridDim.x, seg = 0;
  const int by = w / gridDim.x;
  while (cb >= args.s[seg].nblk) { cb -= args.s[seg].nblk; seg++; }
  const GSeg g = args.s[seg];
  const int rowb = by * 128, colb = cb * 128;
  f32x4 acc[4][4] = {};
  gemm128_loop(A + (size_t)rowb * lda, g.W + (size_t)colb * K, K, lda, K,
               As, Bs, acc);

  const int lane = threadIdx.x & 63, wid = threadIdx.x >> 6;
  const int lr = lane & 15, lq = lane >> 4;
  const int wr = (wid >> 1) * 64, wc = (wid & 1) * 64;

  if (g.epi == 1) {
    // fused Lorentz Q correction (head-aligned 64-col block per wave)
    const int cb64 = colb + wc;
    float mj[4];
#pragma unroll
    for (int j = 0; j < 4; j++) mj[j] = mfl[cb64 + j * 16 + lr];
#pragma unroll
    for (int i = 0; i < 4; i++)
#pragma unroll
      for (int r = 0; r < 4; r++) {
        float p2 = 0.0f, pm2 = 0.0f;
#pragma unroll
        for (int j = 0; j < 4; j++) {
          const float v = acc[i][j][r];
          p2 += v * v;
          pm2 += v * v * mj[j];
        }
#pragma unroll
        for (int off = 8; off >= 1; off >>= 1) {
          p2 += __shfl_xor(p2, off, 64);
          pm2 += __shfl_xor(pm2, off, 64);
        }
        const float qn = sqrtf(p2), qtn = sqrtf(pm2);
        const float sf = (qtn > 1e-6f) ? qn / fmaxf(qtn, 1e-8f) : 0.0f;
        const int row = rowb + wr + i * 16 + lq * 4 + r;
#pragma unroll
        for (int j = 0; j < 4; j++) {
          const int col = cb64 + j * 16 + lr;
          const float v = acc[i][j][r] * (1.0f - 0.5f * sf * mj[j]) * 0.125f;
          g.C[(size_t)row * g.ldc + col] = f2bf(v);
        }
      }
    return;
  }

#pragma unroll
  for (int i = 0; i < 4; i++)
#pragma unroll
    for (int j = 0; j < 4; j++)
#pragma unroll
      for (int r = 0; r < 4; r++) {
        const int row = rowb + wr + i * 16 + lq * 4 + r;
        const int col = colb + wc + j * 16 + lr;
        float v = acc[i][j][r];
        if (g.epi == 2) v = 0.5f * v * (1.0f + erff(v * 0.70710678118654752f));
        else if (g.epi == 3) v = v / (1.0f + __expf(-v));
        g.C[(size_t)row * g.ldc + col] = f2bf(v);
      }
}

// ---------------------------------------------------------------------------
// Wo projection split-K x2, 128x64 tiles: Out += att @ Wo^T partial.
// Out (d_out) holds x. grid (12,32,2) = 768 blocks = 3/CU (was 1.5/CU).
// ---------------------------------------------------------------------------
__global__ __launch_bounds__(256) void gemm128_wo_splitk(
    const u16* __restrict__ A, const u16* __restrict__ W,
    float* __restrict__ Out) {
  __shared__ __align__(16) u16 As[256][32];
  __shared__ __align__(16) u16 Bs[128][32];
  const int w = xcd_work_id();
  const int bx = w % gridDim.x;
  const int by = (w / gridDim.x) % gridDim.y;
  const int z = w / (gridDim.x * gridDim.y);
  const int rowb = by * 128, colb = bx * 64;
  f32x4 acc[4][2] = {};
  gemm128x64_loop(A + (size_t)rowb * 768 + z * 384,
                  W + (size_t)colb * 768 + z * 384, 384, 768, 768,
                  As, Bs, acc);

  const int lane = threadIdx.x & 63, wid = threadIdx.x >> 6;
  const int lr = lane & 15, lq = lane >> 4;
  const int wr = (wid >> 1) * 64, wc = (wid & 1) * 32;
#pragma unroll
  for (int i = 0; i < 4; i++)
#pragma unroll
    for (int j = 0; j < 2; j++)
#pragma unroll
      for (int r = 0; r < 4; r++) {
        const int row = rowb + wr + i * 16 + lq * 4 + r;
        const int col = colb + wc + j * 16 + lr;
        atomicAdd(&Out[(size_t)row * 768 + col], acc[i][j][r]);
      }
}

// ---------------------------------------------------------------------------
// FFN2 split-K x4 (R17 config, best measured): Out += 0.5*partial.
// Out holds x1. grid (6,32,4), XCD-swizzled.
// ---------------------------------------------------------------------------
__global__ __launch_bounds__(256) void ffn2_splitk(
    const u16* __restrict__ H1, const u16* __restrict__ Ht,
    const u16* __restrict__ Hs, const u16* __restrict__ W2,
    const u16* __restrict__ W2t, const u16* __restrict__ W2s,
    float* __restrict__ Out) {
  __shared__ __align__(16) u16 As[256][32];
  __shared__ __align__(16) u16 Bs[256][32];
  const int w = xcd_work_id();
  const int bx = w % gridDim.x;
  const int by = (w / gridDim.x) % gridDim.y;
  const int z = w / (gridDim.x * gridDim.y);
  const int rowb = by * 128, colb = bx * 128;
  f32x4 acc[4][4] = {};
  if (z == 0)
    gemm128_loop(H1 + (size_t)rowb * 3072, W2 + (size_t)colb * 3072,
                 1536, 3072, 3072, As, Bs, acc);
  else if (z == 1)
    gemm128_loop(H1 + (size_t)rowb * 3072 + 1536,
                 W2 + (size_t)colb * 3072 + 1536,
                 1536, 3072, 3072, As, Bs, acc);
  else if (z == 2)
    gemm128_loop(Ht + (size_t)rowb * 1536, W2t + (size_t)colb * 1536,
                 1536, 1536, 1536, As, Bs, acc);
  else
    gemm128_loop(Hs + (size_t)rowb * 1536, W2s + (size_t)colb * 1536,
                 1536, 1536, 1536, As, Bs, acc);

  const int lane = threadIdx.x & 63, wid = threadIdx.x >> 6;
  const int lr = lane & 15, lq = lane >> 4;
  const int wr = (wid >> 1) * 64, wc = (wid & 1) * 64;
#pragma unroll
  for (int i = 0; i < 4; i++)
#pragma unroll
    for (int j = 0; j < 4; j++)
#pragma unroll
      for (int r = 0; r < 4; r++) {
        const int row = rowb + wr + i * 16 + lq * 4 + r;
        const int col = colb + wc + j * 16 + lr;
        atomicAdd(&Out[(size_t)row * 768 + col], 0.5f * acc[i][j][r]);
      }
}

// ---------------------------------------------------------------------------
// Flash attention producer, causal, KV-split (R13, unchanged). QBLK=64,
// 4 waves. Per bh: 80 chunks; qt<8 writes final; else (O,m,l) partial.
// ---------------------------------------------------------------------------
__global__ __launch_bounds__(256) void flash_attn_k(
    const u16* __restrict__ Qc, const u16* __restrict__ Kb,
    const u16* __restrict__ Vb, u16* __restrict__ O,
    float* __restrict__ Pn, float* __restrict__ Ph) {
  __shared__ __align__(16) u16 Ks[64][40];
  __shared__ __align__(16) u16 Vt[64][72];
  __shared__ __align__(16) u16 Ps[4][16][72];
  const int tid = threadIdx.x, wid = tid >> 6, lane = tid & 63;
  const int lr = lane & 15, lq = lane >> 4;

  // decode blockIdx.x -> (qt, c); qt descending so long chunks launch first
  int bx = blockIdx.x, qt = 0, c = 0;
  for (int q = 31; q >= 0; --q) {
    const int nc = (q < 8) ? 1 : (q / 8 + 1);
    if (bx < nc) { qt = q; c = bx; break; }
    bx -= nc;
  }
  const int nt = qt + 1;
  const int t0 = c * 8;
  const int t1 = (t0 + 8 < nt) ? t0 + 8 : nt;

  const int qb = qt * 64;
  const int bh = blockIdx.y;
  const int b = bh / 12, h = bh % 12;
  const int q0 = qb + wid * 16;
  const size_t base = (size_t)b * 2048 * 768 + h * 64;

  bfrag aq[2];
  aq[0] = ldfrag(Qc + base + (size_t)(q0 + lr) * 768 + lq * 8);
  aq[1] = ldfrag(Qc + base + (size_t)(q0 + lr) * 768 + 32 + lq * 8);

  f32x4 o[4] = {};
  float mrow[4] = {NEG_BIG, NEG_BIG, NEG_BIG, NEG_BIG};
  float lrow[4] = {0.0f, 0.0f, 0.0f, 0.0f};

  const int krow = tid >> 3;        // 0..31
  const int kcol = (tid & 7) * 8;
  const int vkey = tid & 31;
  const int vdg = tid >> 5;         // 0..7

  const u16* kp = Kb + base + (size_t)(t0 * 64 + krow) * 768 + kcol;
  const u16* vp = Vb + base + (size_t)(t0 * 64 + vkey) * 768 + vdg * 8;

  uint4 kv0, kv1, vv0, vv1;
  __builtin_memcpy(&kv0, kp, 16);
  __builtin_memcpy(&kv1, kp + (size_t)32 * 768, 16);
  __builtin_memcpy(&vv0, vp, 16);
  __builtin_memcpy(&vv1, vp + (size_t)32 * 768, 16);

  for (int kt = t0; kt < t1; kt++) {
    __syncthreads();
    __builtin_memcpy(&Ks[krow][kcol], &kv0, 16);
    __builtin_memcpy(&Ks[krow + 32][kcol], &kv1, 16);
    {
      union { uint4 u; u16 s[8]; } a, b2;
      a.u = vv0; b2.u = vv1;
#pragma unroll
      for (int j = 0; j < 8; j++) {
        Vt[vdg * 8 + j][vkey] = a.s[j];
        Vt[vdg * 8 + j][vkey + 32] = b2.s[j];
      }
    }
    __syncthreads();
    if (kt + 1 < t1) {
      const size_t koff = (size_t)(kt + 1 - t0) * 64 * 768;
      __builtin_memcpy(&kv0, kp + koff, 16);
      __builtin_memcpy(&kv1, kp + koff + (size_t)32 * 768, 16);
      __builtin_memcpy(&vv0, vp + koff, 16);
      __builtin_memcpy(&vv1, vp + koff + (size_t)32 * 768, 16);
    }

    const int kbk = kt * 64;
    {
      f32x4 s4[4] = {};
#pragma unroll
      for (int kg = 0; kg < 2; kg++) {
#pragma unroll
        for (int cc = 0; cc < 4; cc++) {
          bfrag bk = ldfrag(&Ks[cc * 16 + lr][kg * 32 + lq * 8]);
          s4[cc] = MFMA(aq[kg], bk, s4[cc]);
        }
      }
#pragma unroll
      for (int r = 0; r < 4; r++) {
        const int q = q0 + lq * 4 + r;
        float v[4];
        float mx = NEG_BIG;
#pragma unroll
        for (int cc = 0; cc < 4; cc++) {
          v[cc] = (kbk + cc * 16 + lr > q) ? NEG_BIG : s4[cc][r];
          mx = fmaxf(mx, v[cc]);
        }
#pragma unroll
        for (int off = 8; off >= 1; off >>= 1)
          mx = fmaxf(mx, __shfl_xor(mx, off, 16));
        const float mn = fmaxf(mrow[r], mx);
        const float alpha = __expf(mrow[r] - mn);
        float sm = 0.0f;
        float p[4];
#pragma unroll
        for (int cc = 0; cc < 4; cc++) {
          p[cc] = __expf(v[cc] - mn);
          sm += p[cc];
        }
#pragma unroll
        for (int off = 8; off >= 1; off >>= 1) sm += __shfl_xor(sm, off, 16);
        lrow[r] = lrow[r] * alpha + sm;
        mrow[r] = mn;
#pragma unroll
        for (int dt = 0; dt < 4; dt++) o[dt][r] *= alpha;
#pragma unroll
        for (int cc = 0; cc < 4; cc++)
          Ps[wid][lq * 4 + r][cc * 16 + lr] = f2bf(p[cc]);
      }
      __threadfence_block();
      bfrag pf0 = ldfrag(&Ps[wid][lr][lq * 8]);
      bfrag pf1 = ldfrag(&Ps[wid][lr][32 + lq * 8]);
#pragma unroll
      for (int dt = 0; dt < 4; dt++) {
        bfrag v0 = ldfrag(&Vt[dt * 16 + lr][lq * 8]);
        bfrag v1 = ldfrag(&Vt[dt * 16 + lr][32 + lq * 8]);
        o[dt] = MFMA(pf0, v0, o[dt]);
        o[dt] = MFMA(pf1, v1, o[dt]);
      }
    }
  }

  if (qt < 8) {
    // final: normalize and write bf16
#pragma unroll
    for (int r = 0; r < 4; r++) {
      const float inv = 1.0f / fmaxf(lrow[r], 1e-30f);
      const int q = q0 + lq * 4 + r;
#pragma unroll
      for (int dt = 0; dt < 4; dt++)
        O[base + (size_t)q * 768 + dt * 16 + lr] = f2bf(o[dt][r] * inv);
    }
  } else {
    // partial: slot s = bh*72 + off(qt) + c
    int off = 0;
    for (int j = 8; j < qt; ++j) off += j / 8 + 1;
    const int s = bh * 72 + off + c;
    float* Op = (s < 1536) ? Pn + (size_t)s * 4096
                           : Ph + (size_t)(s - 1536) * 4096;
    float* lmp = Ph + 786432 + (size_t)s * 128;
#pragma unroll
    for (int r = 0; r < 4; r++) {
      const int row = wid * 16 + lq * 4 + r;
#pragma unroll
      for (int dt = 0; dt < 4; dt++)
        Op[(size_t)row * 64 + dt * 16 + lr] = o[dt][r];
      if (lr == 0) { lmp[row] = mrow[r]; lmp[64 + row] = lrow[r]; }
    }
  }
}

// ---------------------------------------------------------------------------
// Merge partials for qt in [8,32): O = sum_c exp(m_c-m_g)*O_c / l_g.
// grid (24, 24): x = qt-8, y = bh.
// ---------------------------------------------------------------------------
__global__ __launch_bounds__(256) void attn_merge_k(
    const float* __restrict__ Pn, const float* __restrict__ Ph,
    u16* __restrict__ O) {
  const int qt = 8 + blockIdx.x;
  const int bh = blockIdx.y;
  const int b = bh / 12, h = bh % 12;
  const int nc = qt / 8 + 1;
  int off = 0;
  for (int j = 8; j < qt; ++j) off += j / 8 + 1;
  const int s0 = bh * 72 + off;
  const int row = threadIdx.x >> 2;
  const int c0 = (threadIdx.x & 3) * 16;
  const float* lmb = Ph + 786432;

  float mg = NEG_BIG;
  for (int cc = 0; cc < nc; ++cc)
    mg = fmaxf(mg, lmb[(size_t)(s0 + cc) * 128 + row]);

  float acc[16];
#pragma unroll
  for (int j = 0; j < 16; j++) acc[j] = 0.0f;
  float lg = 0.0f;
  for (int cc = 0; cc < nc; ++cc) {
    const int s = s0 + cc;
    const float mcv = lmb[(size_t)s * 128 + row];
    const float coef = __expf(mcv - mg);
    lg += coef * lmb[(size_t)s * 128 + 64 + row];
    const float* Op = (s < 1536) ? Pn + (size_t)s * 4096
                                 : Ph + (size_t)(s - 1536) * 4096;
    const float* rp = Op + (size_t)row * 64 + c0;
#pragma unroll
    for (int g = 0; g < 4; g++) {
      float4 v;
      __builtin_memcpy(&v, rp + g * 4, 16);
      acc[g * 4 + 0] += coef * v.x;
      acc[g * 4 + 1] += coef * v.y;
      acc[g * 4 + 2] += coef * v.z;
      acc[g * 4 + 3] += coef * v.w;
    }
  }
  const float inv = 1.0f / fmaxf(lg, 1e-30f);
  const int q = qt * 64 + row;
  const size_t ob = (size_t)b * 2048 * 768 + h * 64 + (size_t)q * 768 + c0;
#pragma unroll
  for (int j = 0; j < 16; j++) O[ob + j] = f2bf(acc[j] * inv);
}

// ---------------------------------------------------------------------------
extern "C" void kernel_launch(void* const* d_in, const int* in_sizes, int n_in,
                              void* d_out, int out_size, void* d_ws,
                              size_t ws_size, hipStream_t stream) {
  (void)in_sizes; (void)n_in; (void)out_size; (void)ws_size;
  const float* x = (const float*)d_in[0];
  const void* mask = d_in[2];

  char* ws = (char*)d_ws;
  u16* Wb  = (u16*)(ws);                        // bf16 arena, 23599104 B
  u16* n1h = (u16*)(ws + 23599104);             // 4096x3072 bf16 (h1 / attn partials)
  u16* Qb  = (u16*)(ws + 48764928);             // 4096x768 (later n2)
  u16* Kb2 = (u16*)(ws + 55056384);             // 4096x768
  u16* Vb2 = (u16*)(ws + 61347840);             // 4096x768
  u16* att = (u16*)(ws + 67639296);             // 4096x768 att, later ht (x1536)
  u16* hs  = (u16*)(ws + 80222208);             // 4096x1536 (attn partial spill)
  float* mfl = (float*)(ws + 92805120);         // 768 floats
  float* x1 = (float*)d_out;                    // x / x1 fp32 live in d_out
  float* Pn = (float*)n1h;                      // 1536 partial slots x 4096 f32
  float* Ph = (float*)hs;                       // 192 slots + m/l at +786432 f32

  u16* Wq = Wb + 0,        *Wk = Wb + 589824,   *Wv = Wb + 1179648;
  u16* Wo = Wb + 1769472,  *w1 = Wb + 2359296,  *w1t = Wb + 4718592;
  u16* w1s = Wb + 5898240, *w2 = Wb + 7077888,  *w2t = Wb + 9437184;
  u16* w2s = Wb + 10616832;
  u16* n1w = Wb + 11796480, *n1b = Wb + 11797248;
  u16* n2w = Wb + 11798016, *n2b = Wb + 11798784;

  Segs sg;
  const int srcidx[14] = {3, 4, 5, 6, 7, 9, 11, 8, 10, 12, 13, 14, 15, 16};
  const int offs[14] = {0, 589824, 1179648, 1769472, 2359296, 4718592,
                        5898240, 7077888, 9437184, 10616832,
                        11796480, 11797248, 11798016, 11798784};
  const int ns[14] = {589824, 589824, 589824, 589824, 2359296, 1179648,
                      1179648, 2359296, 1179648, 1179648, 768, 768, 768, 768};
  const int mms[14] = {0, 0, 0, 0, 0, 1, 2, 0, 0, 0, 0, 0, 0, 0};
  for (int i = 0; i < 14; i++) {
    sg.src[i] = d_in[srcidx[i]];
    sg.off[i] = offs[i];
    sg.n[i] = ns[i];
    sg.mmode[i] = mms[i];
  }

  mask_conv_k<<<1, 256, 0, stream>>>(mask, mfl);
  convert_k<<<dim3(2304, 14), 256, 0, stream>>>(sg, Wb, mfl);

  // n1 = mink_norm(x); also seed d_out with x (residual base for Wo atomics)
  mink_norm_k<<<4096, 256, 0, stream>>>(x, mfl, n1w, n1b, n1h, x1);

  // Q,K,V fused (N=2304), XCD-swizzled. seg0 epi=1: fused Lorentz qcorr.
  GArgs qkv;
  qkv.s[0] = {Wq, Qb, 768, 6, 1};
  qkv.s[1] = {Wk, Kb2, 768, 6, 0};
  qkv.s[2] = {Wv, Vb2, 768, 6, 0};
  gemm128_fused<<<dim3(18, 32), 256, 0, stream>>>(n1h, 768, 768, qkv, mfl);

  // flash attention: 80 chunks/bh, partials into Pn/Ph, then merge
  flash_attn_k<<<dim3(80, 24), 256, 0, stream>>>(Qb, Kb2, Vb2, att, Pn, Ph);
  attn_merge_k<<<dim3(24, 24), 256, 0, stream>>>(Pn, Ph, att);

  // x1 = x + att @ Wo^T  (split-K x2 atomic, 128x64 tiles, 768 blocks)
  gemm128_wo_splitk<<<dim3(12, 32, 2), 256, 0, stream>>>(att, Wo, x1);

  // n2 = mink_norm(x1) -> Qb (mask folded into FFN1 weights)
  mink_norm_k<<<4096, 256, 0, stream>>>(x1, mfl, n2w, n2b, Qb, nullptr);

  // FFN1 fused (N=6144): h1 = gelu(n2@w1^T), ht = silu(n2@w1t_m^T),
  // hs = gelu(n2@w1s_m^T), XCD-swizzled
  GArgs ffn1;
  ffn1.s[0] = {w1, n1h, 3072, 24, 2};
  ffn1.s[1] = {w1t, att, 1536, 12, 3};
  ffn1.s[2] = {w1s, hs, 1536, 12, 2};
  gemm128_fused<<<dim3(48, 32), 256, 0, stream>>>(Qb, 768, 768, ffn1, mfl);

  // out = x1 + 0.5*(h1@w2^T + ht@w2_t^T + hs@w2_s^T), split-K x4 atomic
  ffn2_splitk<<<dim3(6, 32, 4), 256, 0, stream>>>(n1h, att, hs, w2, w2t, w2s,
                                                  (float*)d_out);
}

// Round 12
// 411.280 us; speedup vs baseline: 1.0786x; 1.0247x over previous
//
#include <hip/hip_runtime.h>

// LorentzBlock: B=2, L=2048, D=768, H=12, DH=64, DFF=3072
// R22: (a) Wo reverted to 128^2 x2 split (R21's 128x64 likely -4us, same
// mechanism as R20's ffn2 regression: more staging traffic, wall unchanged);
// (b) flash-decode chunk 8->4 tiles: grid (144,24)=3456 blocks (vs 1920),
// critical path 4 kv-tiles. Partials go fp16 (fp32 doesn't fit: 54MB >
// 37.7MB free; fp16 keeps 10 mantissa bits -> absmax unaffected).
// m/l fp32 at hs+4MB. Merge nc up to 8, grid (28,24).
// Keeps qcorr-fused QKV, R17 depth-2 loop + XCD swizzle, ffn2 x4 (floor).

typedef unsigned short u16;
typedef __bf16 bfrag __attribute__((ext_vector_type(8)));
typedef float f32x4 __attribute__((ext_vector_type(4)));

#define MFMA(a, b, c) __builtin_amdgcn_mfma_f32_16x16x32_bf16(a, b, c, 0, 0, 0)
#define NEG_BIG (-30000.0f)
#define ASYNC16(g, l)                                                        \
  __builtin_amdgcn_global_load_lds(                                          \
      (const __attribute__((address_space(1))) unsigned int*)(g),            \
      (__attribute__((address_space(3))) unsigned int*)(l), 16, 0, 0)

__device__ __forceinline__ float bf2f(u16 u) {
  unsigned int v = ((unsigned int)u) << 16;
  float f; __builtin_memcpy(&f, &v, 4); return f;
}
__device__ __forceinline__ u16 f2bf(float f) {
  unsigned int v; __builtin_memcpy(&v, &f, 4);
  v += 0x7fffu + ((v >> 16) & 1u);   // RNE
  return (u16)(v >> 16);
}
__device__ __forceinline__ u16 f2h(float f) {
  _Float16 h = (_Float16)f; u16 u; __builtin_memcpy(&u, &h, 2); return u;
}
__device__ __forceinline__ float h2f(u16 u) {
  _Float16 h; __builtin_memcpy(&h, &u, 2); return (float)h;
}
__device__ __forceinline__ bfrag ldfrag(const u16* p) {
  bfrag v; __builtin_memcpy(&v, p, 16); return v;
}

// XCD-chunked bijective swizzle of the linear workgroup id. Requires
// nwg % 8 == 0 (all call sites comply); identity fallback otherwise.
__device__ __forceinline__ int xcd_work_id() {
  const int nx = gridDim.x, ny = gridDim.y;
  const int nwg = nx * ny * gridDim.z;
  const int orig = blockIdx.x + nx * (blockIdx.y + ny * blockIdx.z);
  if (nwg & 7) return orig;
  return (orig & 7) * (nwg >> 3) + (orig >> 3);
}

// ---------------------------------------------------------------------------
// Mask canonicalization -> float[768].
// ---------------------------------------------------------------------------
__global__ __launch_bounds__(256) void mask_conv_k(const void* __restrict__ mask,
                                                   float* __restrict__ mfl) {
  __shared__ int msh;
  if (threadIdx.x == 0) msh = 0;
  __syncthreads();
  const unsigned int* w = (const unsigned int*)mask;
  if (threadIdx.x < 192) {
    const unsigned int v = w[threadIdx.x];
    if ((v & 0xFFFFu) == 0x3F80u) atomicOr(&msh, 4);
    else if (v == 0x3F800000u) atomicOr(&msh, 2);
    else if (v >= 2u) atomicOr(&msh, 1);
  }
  __syncthreads();
  const int m = msh;
  const int mode = (m & 4) ? 3 : (m & 2) ? 2 : (m & 1) ? 1 : 0;
  for (int i = threadIdx.x; i < 768; i += 256) {
    int b;
    if (mode == 3) b = ((const u16*)mask)[i] != 0;
    else if (mode == 2) b = ((const float*)mask)[i] != 0.0f;
    else if (mode == 1) b = ((const unsigned char*)mask)[i] != 0;
    else b = ((const int*)mask)[i] != 0;
    mfl[i] = (float)b;
  }
}

// ---------------------------------------------------------------------------
// Convert fp32 weight segments -> bf16 arena. mmode: 0 none, 1 *m[k],
// 2 *(1-m[k]) with k = i % 768 (mask fold for w1_t / w1_s).
// ---------------------------------------------------------------------------
struct Segs {
  const void* src[14];
  int off[14];
  int n[14];
  int mmode[14];
};

__global__ __launch_bounds__(256) void convert_k(Segs segs, u16* __restrict__ dstb,
                                                 const float* __restrict__ mfl) {
  const int seg = blockIdx.y;
  const int n = segs.n[seg];
  const int mm = segs.mmode[seg];
  u16* dst = dstb + segs.off[seg];
  const float* src = (const float*)segs.src[seg];
  for (int i = (blockIdx.x * 256 + threadIdx.x) * 4; i < n; i += gridDim.x * 1024) {
    float4 v;
    __builtin_memcpy(&v, src + i, 16);
    if (mm) {
      const int k = i % 768;
      float m0 = mfl[k], m1 = mfl[k + 1], m2 = mfl[k + 2], m3 = mfl[k + 3];
      if (mm == 2) { m0 = 1.f - m0; m1 = 1.f - m1; m2 = 1.f - m2; m3 = 1.f - m3; }
      v.x *= m0; v.y *= m1; v.z *= m2; v.w *= m3;
    }
    dst[i] = f2bf(v.x); dst[i + 1] = f2bf(v.y);
    dst[i + 2] = f2bf(v.z); dst[i + 3] = f2bf(v.w);
  }
}

// ---------------------------------------------------------------------------
// Minkowski LayerNorm. fp32 input, bf16 output. Optionally copies the raw
// input row to Xcopy (fp32) -- seeds d_out with x for the Wo split-K atomics.
// ---------------------------------------------------------------------------
__global__ __launch_bounds__(256) void mink_norm_k(
    const float* __restrict__ X, const float* __restrict__ mf,
    const u16* __restrict__ w, const u16* __restrict__ bias,
    u16* __restrict__ Y, float* __restrict__ Xcopy) {
  __shared__ float red[8];
  const int row = blockIdx.x, tid = threadIdx.x;
  const int wid = tid >> 6, lane = tid & 63;
  const size_t roff = (size_t)row * 768;

  float xv[3], mv[3];
  int idx[3];
#pragma unroll
  for (int i = 0; i < 3; i++) {
    idx[i] = tid + i * 256;
    xv[i] = X[roff + idx[i]];
    mv[i] = mf[idx[i]];
  }
  if (Xcopy) {
#pragma unroll
    for (int i = 0; i < 3; i++) Xcopy[roff + idx[i]] = xv[i];
  }
  float s = xv[0] + xv[1] + xv[2];
#pragma unroll
  for (int o = 32; o >= 1; o >>= 1) s += __shfl_xor(s, o, 64);
  if (lane == 0) red[wid] = s;
  __syncthreads();
  const float mean = (red[0] + red[1] + red[2] + red[3]) * (1.0f / 768.0f);
  __syncthreads();

  float xc[3], ss = 0.0f, sm = 0.0f;
#pragma unroll
  for (int i = 0; i < 3; i++) {
    xc[i] = xv[i] - mean;
    ss += xc[i] * xc[i];
    sm += xc[i] * xc[i] * mv[i];
  }
#pragma unroll
  for (int o = 32; o >= 1; o >>= 1) {
    ss += __shfl_xor(ss, o, 64);
    sm += __shfl_xor(sm, o, 64);
  }
  if (lane == 0) { red[wid] = ss; red[4 + wid] = sm; }
  __syncthreads();
  const float sumsq = red[0] + red[1] + red[2] + red[3];
  const float summ = red[4] + red[5] + red[6] + red[7];
  const float var = sumsq * (1.0f / 768.0f);
  const float eta = sumsq - 2.0f * summ;
  const float rs = 1.0f / sqrtf(var + 1e-5f);
  const float re = 1.0f / sqrtf(fabsf(eta) + 1e-5f);

#pragma unroll
  for (int i = 0; i < 3; i++) {
    const float xn = xc[i] * 0.5f * (rs + re);
    Y[roff + idx[i]] = f2bf(bf2f(w[idx[i]]) * xn + bf2f(bias[idx[i]]));
  }
}

// ---------------------------------------------------------------------------
// 128x128 MFMA GEMM core, counted-vmcnt 2-phase double-buffered (R16/R17).
// ---------------------------------------------------------------------------
__device__ __forceinline__ void gemm128_loop(
    const u16* __restrict__ Ab, const u16* __restrict__ Wb2,
    int K, int lda, int ldb, u16 (*As)[32], u16 (*Bs)[32], f32x4 acc[4][4]) {
  const int tid = threadIdx.x;
  const int wid = tid >> 6, lane = tid & 63;
  const int lr = lane & 15, lq = lane >> 4;
  const int srow = wid * 32 + (lane >> 2);
  const int scol = (lane & 3) * 8;
  const u16* ga0 = Ab + (size_t)srow * lda + scol;
  const u16* ga1 = Ab + (size_t)(srow + 16) * lda + scol;
  const u16* gb0 = Wb2 + (size_t)srow * ldb + scol;
  const u16* gb1 = Wb2 + (size_t)(srow + 16) * ldb + scol;
  const int wr = (wid >> 1) * 64, wc = (wid & 1) * 64;
  const int nt = K >> 5;

#define STAGE16(dbuf, k0)                                                    \
  {                                                                          \
    u16* _a0 = &As[(dbuf) * 128 + wid * 32][0];                              \
    u16* _a1 = &As[(dbuf) * 128 + wid * 32 + 16][0];                         \
    u16* _b0 = &Bs[(dbuf) * 128 + wid * 32][0];                              \
    u16* _b1 = &Bs[(dbuf) * 128 + wid * 32 + 16][0];                         \
    ASYNC16(ga0 + (k0), _a0);                                                \
    ASYNC16(ga1 + (k0), _a1);                                                \
    ASYNC16(gb0 + (k0), _b0);                                                \
    ASYNC16(gb1 + (k0), _b1);                                                \
  }

  STAGE16(0, 0);
  for (int t = 0; t < nt; ++t) {
    const int cur = t & 1;
    if (t + 1 < nt) {
      STAGE16(cur ^ 1, (t + 1) << 5);
      __builtin_amdgcn_sched_barrier(0);
      asm volatile("s_waitcnt vmcnt(4)" ::: "memory");
    } else {
      asm volatile("s_waitcnt vmcnt(0)" ::: "memory");
    }
    __builtin_amdgcn_s_barrier();
    __builtin_amdgcn_sched_barrier(0);
    bfrag af[4], bf4[4];
#pragma unroll
    for (int i = 0; i < 4; i++)
      af[i] = ldfrag(&As[cur * 128 + wr + i * 16 + lr][lq * 8]);
#pragma unroll
    for (int j = 0; j < 4; j++)
      bf4[j] = ldfrag(&Bs[cur * 128 + wc + j * 16 + lr][lq * 8]);
#pragma unroll
    for (int i = 0; i < 4; i++)
#pragma unroll
      for (int j = 0; j < 4; j++)
        acc[i][j] = MFMA(af[i], bf4[j], acc[i][j]);
    asm volatile("s_waitcnt lgkmcnt(0)" ::: "memory");
    __builtin_amdgcn_sched_barrier(0);
    __builtin_amdgcn_s_barrier();
  }
#undef STAGE16
}

// ---------------------------------------------------------------------------
// Fused multi-segment GEMM, bf16 out: C_seg = epi(A @ Wseg^T).
// epi: 0 none, 1 Lorentz-Q correction (fused qcorr), 2 gelu, 3 silu.
// epi==1: each wave's 64 output cols are one head-aligned block; per row,
// q2/qm2 reduce over j(4 regs) x lr(16 lanes) via shfl_xor 8..1 (stays in
// lq group), then q *= (1 - 0.5*sf*m) * 0.125 (flash pre-scale folded).
// ---------------------------------------------------------------------------
struct GSeg { const u16* W; u16* C; int ldc; int nblk; int epi; };
struct GArgs { GSeg s[3]; };

__global__ __launch_bounds__(256) void gemm128_fused(
    const u16* __restrict__ A, int lda, int K, GArgs args,
    const float* __restrict__ mfl) {
  __shared__ __align__(16) u16 As[256][32];
  __shared__ __align__(16) u16 Bs[256][32];
  const int w = xcd_work_id();
  int cb = w % gridDim.x, seg = 0;
  const int by = w / gridDim.x;
  while (cb >= args.s[seg].nblk) { cb -= args.s[seg].nblk; seg++; }
  const GSeg g = args.s[seg];
  const int rowb = by * 128, colb = cb * 128;
  f32x4 acc[4][4] = {};
  gemm128_loop(A + (size_t)rowb * lda, g.W + (size_t)colb * K, K, lda, K,
               As, Bs, acc);

  const int lane = threadIdx.x & 63, wid = threadIdx.x >> 6;
  const int lr = lane & 15, lq = lane >> 4;
  const int wr = (wid >> 1) * 64, wc = (wid & 1) * 64;

  if (g.epi == 1) {
    // fused Lorentz Q correction (head-aligned 64-col block per wave)
    const int cb64 = colb + wc;
    float mj[4];
#pragma unroll
    for (int j = 0; j < 4; j++) mj[j] = mfl[cb64 + j * 16 + lr];
#pragma unroll
    for (int i = 0; i < 4; i++)
#pragma unroll
      for (int r = 0; r < 4; r++) {
        float p2 = 0.0f, pm2 = 0.0f;
#pragma unroll
        for (int j = 0; j < 4; j++) {
          const float v = acc[i][j][r];
          p2 += v * v;
          pm2 += v * v * mj[j];
        }
#pragma unroll
        for (int off = 8; off >= 1; off >>= 1) {
          p2 += __shfl_xor(p2, off, 64);
          pm2 += __shfl_xor(pm2, off, 64);
        }
        const float qn = sqrtf(p2), qtn = sqrtf(pm2);
        const float sf = (qtn > 1e-6f) ? qn / fmaxf(qtn, 1e-8f) : 0.0f;
        const int row = rowb + wr + i * 16 + lq * 4 + r;
#pragma unroll
        for (int j = 0; j < 4; j++) {
          const int col = cb64 + j * 16 + lr;
          const float v = acc[i][j][r] * (1.0f - 0.5f * sf * mj[j]) * 0.125f;
          g.C[(size_t)row * g.ldc + col] = f2bf(v);
        }
      }
    return;
  }

#pragma unroll
  for (int i = 0; i < 4; i++)
#pragma unroll
    for (int j = 0; j < 4; j++)
#pragma unroll
      for (int r = 0; r < 4; r++) {
        const int row = rowb + wr + i * 16 + lq * 4 + r;
        const int col = colb + wc + j * 16 + lr;
        float v = acc[i][j][r];
        if (g.epi == 2) v = 0.5f * v * (1.0f + erff(v * 0.70710678118654752f));
        else if (g.epi == 3) v = v / (1.0f + __expf(-v));
        g.C[(size_t)row * g.ldc + col] = f2bf(v);
      }
}

// ---------------------------------------------------------------------------
// Wo projection split-K x2 (R17 config, 128^2 tiles): Out += att @ Wo^T.
// Out (d_out) holds x. grid (6,32,2), XCD-swizzled.
// ---------------------------------------------------------------------------
__global__ __launch_bounds__(256) void gemm128_wo_splitk(
    const u16* __restrict__ A, const u16* __restrict__ W,
    float* __restrict__ Out) {
  __shared__ __align__(16) u16 As[256][32];
  __shared__ __align__(16) u16 Bs[256][32];
  const int w = xcd_work_id();
  const int bx = w % gridDim.x;
  const int by = (w / gridDim.x) % gridDim.y;
  const int z = w / (gridDim.x * gridDim.y);
  const int rowb = by * 128, colb = bx * 128;
  f32x4 acc[4][4] = {};
  gemm128_loop(A + (size_t)rowb * 768 + z * 384,
               W + (size_t)colb * 768 + z * 384, 384, 768, 768, As, Bs, acc);

  const int lane = threadIdx.x & 63, wid = threadIdx.x >> 6;
  const int lr = lane & 15, lq = lane >> 4;
  const int wr = (wid >> 1) * 64, wc = (wid & 1) * 64;
#pragma unroll
  for (int i = 0; i < 4; i++)
#pragma unroll
    for (int j = 0; j < 4; j++)
#pragma unroll
      for (int r = 0; r < 4; r++) {
        const int row = rowb + wr + i * 16 + lq * 4 + r;
        const int col = colb + wc + j * 16 + lr;
        atomicAdd(&Out[(size_t)row * 768 + col], acc[i][j][r]);
      }
}

// ---------------------------------------------------------------------------
// FFN2 split-K x4 (R17 config, best measured): Out += 0.5*partial.
// Out holds x1. grid (6,32,4), XCD-swizzled.
// ---------------------------------------------------------------------------
__global__ __launch_bounds__(256) void ffn2_splitk(
    const u16* __restrict__ H1, const u16* __restrict__ Ht,
    const u16* __restrict__ Hs, const u16* __restrict__ W2,
    const u16* __restrict__ W2t, const u16* __restrict__ W2s,
    float* __restrict__ Out) {
  __shared__ __align__(16) u16 As[256][32];
  __shared__ __align__(16) u16 Bs[256][32];
  const int w = xcd_work_id();
  const int bx = w % gridDim.x;
  const int by = (w / gridDim.x) % gridDim.y;
  const int z = w / (gridDim.x * gridDim.y);
  const int rowb = by * 128, colb = bx * 128;
  f32x4 acc[4][4] = {};
  if (z == 0)
    gemm128_loop(H1 + (size_t)rowb * 3072, W2 + (size_t)colb * 3072,
                 1536, 3072, 3072, As, Bs, acc);
  else if (z == 1)
    gemm128_loop(H1 + (size_t)rowb * 3072 + 1536,
                 W2 + (size_t)colb * 3072 + 1536,
                 1536, 3072, 3072, As, Bs, acc);
  else if (z == 2)
    gemm128_loop(Ht + (size_t)rowb * 1536, W2t + (size_t)colb * 1536,
                 1536, 1536, 1536, As, Bs, acc);
  else
    gemm128_loop(Hs + (size_t)rowb * 1536, W2s + (size_t)colb * 1536,
                 1536, 1536, 1536, As, Bs, acc);

  const int lane = threadIdx.x & 63, wid = threadIdx.x >> 6;
  const int lr = lane & 15, lq = lane >> 4;
  const int wr = (wid >> 1) * 64, wc = (wid & 1) * 64;
#pragma unroll
  for (int i = 0; i < 4; i++)
#pragma unroll
    for (int j = 0; j < 4; j++)
#pragma unroll
      for (int r = 0; r < 4; r++) {
        const int row = rowb + wr + i * 16 + lq * 4 + r;
        const int col = colb + wc + j * 16 + lr;
        atomicAdd(&Out[(size_t)row * 768 + col], 0.5f * acc[i][j][r]);
      }
}

// ---------------------------------------------------------------------------
// Flash attention producer, causal, KV-split chunk=4. QBLK=64, 4 waves.
// Per bh: 144 blocks. qt<4: single chunk, writes final bf16 att.
// qt>=4: fp16 unnormalized O partial + fp32 (m,l) at slot
//   s = bh*140 + off(qt) + c, off(qt) = sum_{j=4}^{qt-1}(j/4+1).
//   O: s<3072 -> Pn + s*4096 (u16); else Ph + (s-3072)*4096.
//   m/l: Lm + s*128 floats.
// ---------------------------------------------------------------------------
__global__ __launch_bounds__(256) void flash_attn_k(
    const u16* __restrict__ Qc, const u16* __restrict__ Kb,
    const u16* __restrict__ Vb, u16* __restrict__ O,
    u16* __restrict__ Pn, u16* __restrict__ Ph, float* __restrict__ Lm) {
  __shared__ __align__(16) u16 Ks[64][40];
  __shared__ __align__(16) u16 Vt[64][72];
  __shared__ __align__(16) u16 Ps[4][16][72];
  const int tid = threadIdx.x, wid = tid >> 6, lane = tid & 63;
  const int lr = lane & 15, lq = lane >> 4;

  // decode blockIdx.x -> (qt, c); qt descending so long chunks launch first
  int bx = blockIdx.x, qt = 0, c = 0;
  for (int q = 31; q >= 0; --q) {
    const int nc = (q < 4) ? 1 : (q / 4 + 1);
    if (bx < nc) { qt = q; c = bx; break; }
    bx -= nc;
  }
  const int nt = qt + 1;
  const int t0 = c * 4;
  const int t1 = (t0 + 4 < nt) ? t0 + 4 : nt;

  const int qb = qt * 64;
  const int bh = blockIdx.y;
  const int b = bh / 12, h = bh % 12;
  const int q0 = qb + wid * 16;
  const size_t base = (size_t)b * 2048 * 768 + h * 64;

  bfrag aq[2];
  aq[0] = ldfrag(Qc + base + (size_t)(q0 + lr) * 768 + lq * 8);
  aq[1] = ldfrag(Qc + base + (size_t)(q0 + lr) * 768 + 32 + lq * 8);

  f32x4 o[4] = {};
  float mrow[4] = {NEG_BIG, NEG_BIG, NEG_BIG, NEG_BIG};
  float lrow[4] = {0.0f, 0.0f, 0.0f, 0.0f};

  const int krow = tid >> 3;        // 0..31
  const int kcol = (tid & 7) * 8;
  const int vkey = tid & 31;
  const int vdg = tid >> 5;         // 0..7

  const u16* kp = Kb + base + (size_t)(t0 * 64 + krow) * 768 + kcol;
  const u16* vp = Vb + base + (size_t)(t0 * 64 + vkey) * 768 + vdg * 8;

  uint4 kv0, kv1, vv0, vv1;
  __builtin_memcpy(&kv0, kp, 16);
  __builtin_memcpy(&kv1, kp + (size_t)32 * 768, 16);
  __builtin_memcpy(&vv0, vp, 16);
  __builtin_memcpy(&vv1, vp + (size_t)32 * 768, 16);

  for (int kt = t0; kt < t1; kt++) {
    __syncthreads();
    __builtin_memcpy(&Ks[krow][kcol], &kv0, 16);
    __builtin_memcpy(&Ks[krow + 32][kcol], &kv1, 16);
    {
      union { uint4 u; u16 s[8]; } a, b2;
      a.u = vv0; b2.u = vv1;
#pragma unroll
      for (int j = 0; j < 8; j++) {
        Vt[vdg * 8 + j][vkey] = a.s[j];
        Vt[vdg * 8 + j][vkey + 32] = b2.s[j];
      }
    }
    __syncthreads();
    if (kt + 1 < t1) {
      const size_t koff = (size_t)(kt + 1 - t0) * 64 * 768;
      __builtin_memcpy(&kv0, kp + koff, 16);
      __builtin_memcpy(&kv1, kp + koff + (size_t)32 * 768, 16);
      __builtin_memcpy(&vv0, vp + koff, 16);
      __builtin_memcpy(&vv1, vp + koff + (size_t)32 * 768, 16);
    }

    const int kbk = kt * 64;
    {
      f32x4 s4[4] = {};
#pragma unroll
      for (int kg = 0; kg < 2; kg++) {
#pragma unroll
        for (int cc = 0; cc < 4; cc++) {
          bfrag bk = ldfrag(&Ks[cc * 16 + lr][kg * 32 + lq * 8]);
          s4[cc] = MFMA(aq[kg], bk, s4[cc]);
        }
      }
#pragma unroll
      for (int r = 0; r < 4; r++) {
        const int q = q0 + lq * 4 + r;
        float v[4];
        float mx = NEG_BIG;
#pragma unroll
        for (int cc = 0; cc < 4; cc++) {
          v[cc] = (kbk + cc * 16 + lr > q) ? NEG_BIG : s4[cc][r];
          mx = fmaxf(mx, v[cc]);
        }
#pragma unroll
        for (int off = 8; off >= 1; off >>= 1)
          mx = fmaxf(mx, __shfl_xor(mx, off, 16));
        const float mn = fmaxf(mrow[r], mx);
        const float alpha = __expf(mrow[r] - mn);
        float sm = 0.0f;
        float p[4];
#pragma unroll
        for (int cc = 0; cc < 4; cc++) {
          p[cc] = __expf(v[cc] - mn);
          sm += p[cc];
        }
#pragma unroll
        for (int off = 8; off >= 1; off >>= 1) sm += __shfl_xor(sm, off, 16);
        lrow[r] = lrow[r] * alpha + sm;
        mrow[r] = mn;
#pragma unroll
        for (int dt = 0; dt < 4; dt++) o[dt][r] *= alpha;
#pragma unroll
        for (int cc = 0; cc < 4; cc++)
          Ps[wid][lq * 4 + r][cc * 16 + lr] = f2bf(p[cc]);
      }
      __threadfence_block();
      bfrag pf0 = ldfrag(&Ps[wid][lr][lq * 8]);
      bfrag pf1 = ldfrag(&Ps[wid][lr][32 + lq * 8]);
#pragma unroll
      for (int dt = 0; dt < 4; dt++) {
        bfrag v0 = ldfrag(&Vt[dt * 16 + lr][lq * 8]);
        bfrag v1 = ldfrag(&Vt[dt * 16 + lr][32 + lq * 8]);
        o[dt] = MFMA(pf0, v0, o[dt]);
        o[dt] = MFMA(pf1, v1, o[dt]);
      }
    }
  }

  if (qt < 4) {
    // final: normalize and write bf16
#pragma unroll
    for (int r = 0; r < 4; r++) {
      const float inv = 1.0f / fmaxf(lrow[r], 1e-30f);
      const int q = q0 + lq * 4 + r;
#pragma unroll
      for (int dt = 0; dt < 4; dt++)
        O[base + (size_t)q * 768 + dt * 16 + lr] = f2bf(o[dt][r] * inv);
    }
  } else {
    // partial: slot s = bh*140 + off(qt) + c
    int off = 0;
    for (int j = 4; j < qt; ++j) off += j / 4 + 1;
    const int s = bh * 140 + off + c;
    u16* Op = (s < 3072) ? Pn + (size_t)s * 4096
                         : Ph + (size_t)(s - 3072) * 4096;
    float* lmp = Lm + (size_t)s * 128;
#pragma unroll
    for (int r = 0; r < 4; r++) {
      const int row = wid * 16 + lq * 4 + r;
#pragma unroll
      for (int dt = 0; dt < 4; dt++)
        Op[(size_t)row * 64 + dt * 16 + lr] = f2h(o[dt][r]);
      if (lr == 0) { lmp[row] = mrow[r]; lmp[64 + row] = lrow[r]; }
    }
  }
}

// ---------------------------------------------------------------------------
// Merge partials for qt in [4,32): O = sum_c exp(m_c-m_g)*O_c / l_g.
// grid (28, 24): x = qt-4, y = bh. fp16 O partials, fp32 m/l.
// ---------------------------------------------------------------------------
__global__ __launch_bounds__(256) void attn_merge_k(
    const u16* __restrict__ Pn, const u16* __restrict__ Ph,
    const float* __restrict__ Lm, u16* __restrict__ O) {
  const int qt = 4 + blockIdx.x;
  const int bh = blockIdx.y;
  const int b = bh / 12, h = bh % 12;
  const int nc = qt / 4 + 1;
  int off = 0;
  for (int j = 4; j < qt; ++j) off += j / 4 + 1;
  const int s0 = bh * 140 + off;
  const int row = threadIdx.x >> 2;
  const int c0 = (threadIdx.x & 3) * 16;

  float mg = NEG_BIG;
  for (int cc = 0; cc < nc; ++cc)
    mg = fmaxf(mg, Lm[(size_t)(s0 + cc) * 128 + row]);

  float acc[16];
#pragma unroll
  for (int j = 0; j < 16; j++) acc[j] = 0.0f;
  float lg = 0.0f;
  for (int cc = 0; cc < nc; ++cc) {
    const int s = s0 + cc;
    const float mcv = Lm[(size_t)s * 128 + row];
    const float coef = __expf(mcv - mg);
    lg += coef * Lm[(size_t)s * 128 + 64 + row];
    const u16* Op = (s < 3072) ? Pn + (size_t)s * 4096
                               : Ph + (size_t)(s - 3072) * 4096;
    const u16* rp = Op + (size_t)row * 64 + c0;
    u16 tv[16];
    __builtin_memcpy(tv, rp, 32);
#pragma unroll
    for (int j = 0; j < 16; j++) acc[j] += coef * h2f(tv[j]);
  }
  const float inv = 1.0f / fmaxf(lg, 1e-30f);
  const int q = qt * 64 + row;
  const size_t ob = (size_t)b * 2048 * 768 + h * 64 + (size_t)q * 768 + c0;
#pragma unroll
  for (int j = 0; j < 16; j++) O[ob + j] = f2bf(acc[j] * inv);
}

// ---------------------------------------------------------------------------
extern "C" void kernel_launch(void* const* d_in, const int* in_sizes, int n_in,
                              void* d_out, int out_size, void* d_ws,
                              size_t ws_size, hipStream_t stream) {
  (void)in_sizes; (void)n_in; (void)out_size; (void)ws_size;
  const float* x = (const float*)d_in[0];
  const void* mask = d_in[2];

  char* ws = (char*)d_ws;
  u16* Wb  = (u16*)(ws);                        // bf16 arena, 23599104 B
  u16* n1h = (u16*)(ws + 23599104);             // 4096x3072 bf16 (h1 / attn partials)
  u16* Qb  = (u16*)(ws + 48764928);             // 4096x768 (later n2)
  u16* Kb2 = (u16*)(ws + 55056384);             // 4096x768
  u16* Vb2 = (u16*)(ws + 61347840);             // 4096x768
  u16* att = (u16*)(ws + 67639296);             // 4096x768 att, later ht (x1536)
  u16* hs  = (u16*)(ws + 80222208);             // 4096x1536 (attn partial spill)
  float* mfl = (float*)(ws + 92805120);         // 768 floats
  float* x1 = (float*)d_out;                    // x / x1 fp32 live in d_out
  u16* Pn16 = n1h;                              // fp16 O-partials, slots 0..3071
  u16* Ph16 = hs;                               // fp16 O-partials, slots 3072..3359
  float* Lm = (float*)(ws + 80222208 + 4194304); // m/l: 3360 slots x 128 f32

  u16* Wq = Wb + 0,        *Wk = Wb + 589824,   *Wv = Wb + 1179648;
  u16* Wo = Wb + 1769472,  *w1 = Wb + 2359296,  *w1t = Wb + 4718592;
  u16* w1s = Wb + 5898240, *w2 = Wb + 7077888,  *w2t = Wb + 9437184;
  u16* w2s = Wb + 10616832;
  u16* n1w = Wb + 11796480, *n1b = Wb + 11797248;
  u16* n2w = Wb + 11798016, *n2b = Wb + 11798784;

  Segs sg;
  const int srcidx[14] = {3, 4, 5, 6, 7, 9, 11, 8, 10, 12, 13, 14, 15, 16};
  const int offs[14] = {0, 589824, 1179648, 1769472, 2359296, 4718592,
                        5898240, 7077888, 9437184, 10616832,
                        11796480, 11797248, 11798016, 11798784};
  const int ns[14] = {589824, 589824, 589824, 589824, 2359296, 1179648,
                      1179648, 2359296, 1179648, 1179648, 768, 768, 768, 768};
  const int mms[14] = {0, 0, 0, 0, 0, 1, 2, 0, 0, 0, 0, 0, 0, 0};
  for (int i = 0; i < 14; i++) {
    sg.src[i] = d_in[srcidx[i]];
    sg.off[i] = offs[i];
    sg.n[i] = ns[i];
    sg.mmode[i] = mms[i];
  }

  mask_conv_k<<<1, 256, 0, stream>>>(mask, mfl);
  convert_k<<<dim3(2304, 14), 256, 0, stream>>>(sg, Wb, mfl);

  // n1 = mink_norm(x); also seed d_out with x (residual base for Wo atomics)
  mink_norm_k<<<4096, 256, 0, stream>>>(x, mfl, n1w, n1b, n1h, x1);

  // Q,K,V fused (N=2304), XCD-swizzled. seg0 epi=1: fused Lorentz qcorr.
  GArgs qkv;
  qkv.s[0] = {Wq, Qb, 768, 6, 1};
  qkv.s[1] = {Wk, Kb2, 768, 6, 0};
  qkv.s[2] = {Wv, Vb2, 768, 6, 0};
  gemm128_fused<<<dim3(18, 32), 256, 0, stream>>>(n1h, 768, 768, qkv, mfl);

  // flash attention: 144 chunks/bh (chunk=4 kv-tiles), fp16 partials, merge
  flash_attn_k<<<dim3(144, 24), 256, 0, stream>>>(Qb, Kb2, Vb2, att,
                                                  Pn16, Ph16, Lm);
  attn_merge_k<<<dim3(28, 24), 256, 0, stream>>>(Pn16, Ph16, Lm, att);

  // x1 = x + att @ Wo^T  (split-K x2 atomic, 128^2 tiles — R17 config)
  gemm128_wo_splitk<<<dim3(6, 32, 2), 256, 0, stream>>>(att, Wo, x1);

  // n2 = mink_norm(x1) -> Qb (mask folded into FFN1 weights)
  mink_norm_k<<<4096, 256, 0, stream>>>(x1, mfl, n2w, n2b, Qb, nullptr);

  // FFN1 fused (N=6144): h1 = gelu(n2@w1^T), ht = silu(n2@w1t_m^T),
  // hs = gelu(n2@w1s_m^T), XCD-swizzled
  GArgs ffn1;
  ffn1.s[0] = {w1, n1h, 3072, 24, 2};
  ffn1.s[1] = {w1t, att, 1536, 12, 3};
  ffn1.s[2] = {w1s, hs, 1536, 12, 2};
  gemm128_fused<<<dim3(48, 32), 256, 0, stream>>>(Qb, 768, 768, ffn1, mfl);

  // out = x1 + 0.5*(h1@w2^T + ht@w2_t^T + hs@w2_s^T), split-K x4 atomic
  ffn2_splitk<<<dim3(6, 32, 4), 256, 0, stream>>>(n1h, att, hs, w2, w2t, w2s,
                                                  (float*)d_out);
}